// Round 2
// baseline (484.409 us; speedup 1.0000x reference)
//
#include <hip/hip_runtime.h>
#include <hip/hip_bf16.h>

// B=32, C=3, H=W=128, D=512, K=512, S=4, NPOS=32768
#define NPOS 32768
#define EPS_GAP 4e-3f
#define MAXSUS 4096

typedef __attribute__((ext_vector_type(8))) short short8;
typedef __attribute__((ext_vector_type(4))) float floatx4;

static __device__ __forceinline__ float bfu(unsigned short h) {
    return __uint_as_float(((unsigned int)h) << 16);
}
static __device__ __forceinline__ unsigned short f2bf(float f) {
    unsigned int u = __float_as_uint(f);
    u = (u + 0x7fffu + ((u >> 16) & 1u)) >> 16;   // RNE
    return (unsigned short)u;
}
static __device__ __forceinline__ float ldin(const void* p, size_t i, int flag) {
    return flag ? bfu(((const unsigned short*)p)[i]) : ((const float*)p)[i];
}

// ---------------------------------------------------------------------------
// Widened sniff: 1024 threads, 16-way d-split per column, LDS reduce.
// ---------------------------------------------------------------------------
__global__ __launch_bounds__(1024) void k_sniff(const void* __restrict__ cb,
                                                int* __restrict__ flag,
                                                int* __restrict__ scnt) {
    __shared__ float s[1024];
    const int t = threadIdx.x;
    const int k = t & 63, g = t >> 6;          // 16 groups x 32 d
    const unsigned short* u = (const unsigned short*)cb;
    float acc = 0.f;
    for (int d = g * 32; d < g * 32 + 32; ++d) {
        float v = bfu(u[(size_t)d * 512 + k]);
        acc = fmaf(v, v, acc);
    }
    s[t] = acc;
    __syncthreads();
    if (t < 64) {
        float a = 0.f;
        #pragma unroll
        for (int g2 = 0; g2 < 16; ++g2) a += s[g2 * 64 + k];
        int ok = (a >= 100.f && a <= 2000.f) ? 1 : 0;
        unsigned long long m = __ballot(ok);
        if (k == 0) {
            *flag = (m == ~0ull) ? 1 : 0;
            *scnt = 0;
        }
    }
}

// ---------------------------------------------------------------------------
__global__ void k_canonW(const void* __restrict__ We, const void* __restrict__ be,
                         const void* __restrict__ Wd, const void* __restrict__ bd,
                         const int* __restrict__ flagp, float* __restrict__ cWe,
                         float* __restrict__ cbe, float* __restrict__ cWd,
                         float* __restrict__ cbd) {
    int e = blockIdx.x * 256 + threadIdx.x;
    const int flag = *flagp;
    if (e < 24576)       cWe[e]         = ldin(We, e, flag);
    else if (e < 25088)  cbe[e - 24576] = ldin(be, e - 24576, flag);
    else if (e < 49664)  cWd[e - 25088] = ldin(Wd, e - 25088, flag);
    else if (e < 49667)  cbd[e - 49664] = ldin(bd, e - 49664, flag);
}

// ---------------------------------------------------------------------------
// cbF fp32 [d][k]; cbT fp32 [k][d]; cbHT/cbLT bf16-split [k][d].
// ---------------------------------------------------------------------------
__global__ __launch_bounds__(256) void k_prepcb(
        const void* __restrict__ cb, const int* __restrict__ flagp,
        float* __restrict__ cbF, float* __restrict__ cbT,
        unsigned short* __restrict__ cbHT, unsigned short* __restrict__ cbLT) {
    __shared__ float tile[64][65];
    const int flag = *flagp;
    const int D0 = blockIdx.x * 64, K0 = blockIdx.y * 64;
    const int t = threadIdx.x;
    for (int it = 0; it < 16; ++it) {
        int r = (t >> 6) + 4 * it, c = t & 63;
        float v = ldin(cb, (size_t)(D0 + r) * 512 + K0 + c, flag);
        cbF[(size_t)(D0 + r) * 512 + K0 + c] = v;
        tile[r][c] = v;
    }
    __syncthreads();
    for (int it = 0; it < 16; ++it) {
        int r = (t >> 6) + 4 * it, c = t & 63;
        float v = tile[c][r];
        size_t o = (size_t)(K0 + r) * 512 + D0 + c;
        cbT[o] = v;
        unsigned short h = f2bf(v);
        cbHT[o] = h;
        cbLT[o] = f2bf(v - bfu(h));
    }
}

// ---------------------------------------------------------------------------
// Widened w2: 256 threads/block, deterministic 4-way tree reduce.
// ---------------------------------------------------------------------------
__global__ __launch_bounds__(256) void k_w2(const float* __restrict__ cbF,
                                            float* __restrict__ w2,
                                            double* __restrict__ w2d) {
    __shared__ double s[256];
    const int t = threadIdx.x;
    const int k = blockIdx.x * 64 + (t & 63);
    const int g = t >> 6;                      // 4 groups x 128 d
    double acc = 0.0;
    for (int d = g * 128; d < g * 128 + 128; ++d) {
        double v = (double)cbF[(size_t)d * 512 + k];
        acc += v * v;
    }
    s[t] = acc;
    __syncthreads();
    if (t < 64) {
        double a = s[t] + s[t + 64] + s[t + 128] + s[t + 192];
        w2[k] = (float)a;
        w2d[k] = a;
    }
}

// ---------------------------------------------------------------------------
// U[k][c*16+u*4+v] = sum_d cbT[k][d]*cWd[c][d][3-u][3-v] + cbd[c]
// ---------------------------------------------------------------------------
__global__ __launch_bounds__(256) void k_udec(
        const float* __restrict__ cbT, const float* __restrict__ cWd,
        const float* __restrict__ cbd, float* __restrict__ U) {
    const int t = threadIdx.x;
    const int k = blockIdx.x * 4 + (t >> 6);
    const int lane = t & 63;
    const int j = lane >> 2, dpart = lane & 3;
    const int u = (j >> 2) & 3, v = j & 3;
    int woff[3];
    #pragma unroll
    for (int m = 0; m < 3; ++m) woff[m] = m * 8192 + (3 - u) * 4 + (3 - v);
    float a0 = 0.f, a1 = 0.f, a2 = 0.f;
    for (int i = 0; i < 128; ++i) {
        int d = dpart * 128 + i;
        float cw = cbT[(size_t)k * 512 + d];
        a0 = fmaf(cw, cWd[woff[0] + d * 16], a0);
        a1 = fmaf(cw, cWd[woff[1] + d * 16], a1);
        a2 = fmaf(cw, cWd[woff[2] + d * 16], a2);
    }
    a0 += __shfl_xor(a0, 1); a0 += __shfl_xor(a0, 2);
    a1 += __shfl_xor(a1, 1); a1 += __shfl_xor(a1, 2);
    a2 += __shfl_xor(a2, 1); a2 += __shfl_xor(a2, 2);
    if (dpart == 0) {
        U[k * 48 +  0 + j] = a0 + cbd[0];
        U[k * 48 + 16 + j] = a1 + cbd[1];
        U[k * 48 + 32 + j] = a2 + cbd[2];
    }
}

// best/second combine: (a1,ak,a2) <- merge (o1,ok,o2)
static __device__ __forceinline__ void bmerge(float& a1, int& ak, float& a2,
                                              float o1, int ok, float o2) {
    if (o1 < a1)      { a2 = fminf(a1, o2); a1 = o1; ak = ok; }
    else if (o1 > a1) { a2 = fminf(a2, o1); }
    else              { a2 = a1; if (ok < ak) ak = ok; }   // exact tie -> gap 0 (suspect)
}

// ---------------------------------------------------------------------------
// FUSED main v5 (wave-independent, ZERO barriers): each wave owns 16
// positions end-to-end. Per 32-d chunk:
//   conv: lane = 1 d (cd=lane&31) x 8 pos (half h=lane>>5) -> z H/L bf16
//         -> wave-PRIVATE zw slab (same-wave lgkm ordering, no barrier)
//   mfma: A-frag 16pos x 32d from own zw; ALL 32 j-tiles (512 codes),
//         acc[32] = 128 VGPRs; B from L2 (cb tables L2-resident)
//   outz: own 16 columns of out_z (64B segments)
// Epilogue per wave: C cols=code j*16+lcol, rows=pos quad*4+r; shfl_xor
// reduce over lcol -> wave-local argmin; fused emb for own 16 pos.
// LDS: 4 x (patch [16][48] fp32 = 3072B | zw H/L [16][40]x2 = 2560B) = 22528B.
// ---------------------------------------------------------------------------
__global__ __launch_bounds__(256, 2) void k_main(
        const void* __restrict__ x, const float* __restrict__ cWe,
        const float* __restrict__ cbe, const int* __restrict__ flagp,
        const unsigned short* __restrict__ cbHT, const unsigned short* __restrict__ cbLT,
        const float* __restrict__ cbT, const float* __restrict__ w2,
        float* __restrict__ out_z, float* __restrict__ out_e,
        int* __restrict__ idx, int* __restrict__ scnt, int* __restrict__ spos,
        int skipTail) {
    __shared__ __align__(16) char smc[22528];

    const int t = threadIdx.x;
    const int wb = t >> 6, lane = t & 63;
    const int quad = lane >> 4, lcol = lane & 15;
    const int cd = lane & 31, h = lane >> 5;
    const int P0 = blockIdx.x * 64;
    const int wp0 = P0 + wb * 16;                  // wave's first position
    const int b = P0 >> 10;
    const int SP0 = (P0 & 1023) + wb * 16;         // wave's spatial base
    const int flag = *flagp;

    float* patchW = (float*)smc + wb * 768;                      // [16][48]
    unsigned short* zw = (unsigned short*)(smc + 12288) + wb * 1280; // H[16][40] | L[16][40]

    // wave-private patch staging: 16 pos x 48 vals, 12 per lane
    #pragma unroll
    for (int q = 0; q < 12; ++q) {
        int e = lane * 12 + q;
        int pid = e / 48, kk = e % 48;
        int c = kk >> 4, r = (kk >> 2) & 3, s = kk & 3;
        int pos = wp0 + pid;
        int bb = pos >> 10, sp = pos & 1023, i = sp >> 5, j = sp & 31;
        patchW[pid * 48 + kk] = ldin(x, ((bb * 3 + c) * 128 + (i * 4 + r)) * 128 + (j * 4 + s), flag);
    }

    floatx4 acc[32];
    #pragma unroll
    for (int j = 0; j < 32; ++j) acc[j] = (floatx4){0.f, 0.f, 0.f, 0.f};

    #pragma unroll 1
    for (int dc = 0; dc < 512; dc += 32) {
        // ---- conv: 1 d x 8 pos per lane (identical FMA order to v3) ----
        const float4* wv = (const float4*)(cWe + (size_t)(dc + cd) * 48);
        const float bias = cbe[dc + cd];
        float za[8];
        #pragma unroll
        for (int p = 0; p < 8; ++p) za[p] = bias;
        #pragma unroll
        for (int q4 = 0; q4 < 12; ++q4) {
            float4 wq = wv[q4];
            #pragma unroll
            for (int p = 0; p < 8; ++p) {
                float4 v = *(const float4*)(patchW + (h * 8 + p) * 48 + q4 * 4);
                za[p] = fmaf(v.x, wq.x, za[p]);
                za[p] = fmaf(v.y, wq.y, za[p]);
                za[p] = fmaf(v.z, wq.z, za[p]);
                za[p] = fmaf(v.w, wq.w, za[p]);
            }
        }
        #pragma unroll
        for (int p = 0; p < 8; ++p) {
            float z = fmaxf(za[p], 0.f);
            unsigned short hh = f2bf(z);
            zw[(h * 8 + p) * 40 + cd] = hh;
            zw[640 + (h * 8 + p) * 40 + cd] = f2bf(z - bfu(hh));
        }

        // ---- mfma: own A-frag, all 512 codes ----
        short8 aH = *(const short8*)(zw + lcol * 40 + quad * 8);
        short8 aL = *(const short8*)(zw + 640 + lcol * 40 + quad * 8);
        #pragma unroll
        for (int j = 0; j < 32; ++j) {
            short8 bH = *(const short8*)(cbHT + (size_t)(j * 16 + lcol) * 512 + dc + quad * 8);
            acc[j] = __builtin_amdgcn_mfma_f32_16x16x32_bf16(aH, bH, acc[j], 0, 0, 0);
            acc[j] = __builtin_amdgcn_mfma_f32_16x16x32_bf16(aL, bH, acc[j], 0, 0, 0);
        }
        if (!flag) {   // fp32 inputs: third term zh*cbL
            #pragma unroll
            for (int j = 0; j < 32; ++j) {
                short8 bL = *(const short8*)(cbLT + (size_t)(j * 16 + lcol) * 512 + dc + quad * 8);
                acc[j] = __builtin_amdgcn_mfma_f32_16x16x32_bf16(aH, bL, acc[j], 0, 0, 0);
            }
        }

        // ---- outz: lane = pos lcol, d-group quad (8 d) ----
        {
            const unsigned short* ph = zw + lcol * 40 + quad * 8;
            const unsigned short* pl = zw + 640 + lcol * 40 + quad * 8;
            ushort4 h0 = *(const ushort4*)(ph);
            ushort4 h1 = *(const ushort4*)(ph + 4);
            ushort4 l0 = *(const ushort4*)(pl);
            ushort4 l1 = *(const ushort4*)(pl + 4);
            size_t base = (size_t)(b * 512 + dc + quad * 8) * 1024 + SP0 + lcol;
            out_z[base         ] = bfu(h0.x) + bfu(l0.x);
            out_z[base + 1024  ] = bfu(h0.y) + bfu(l0.y);
            out_z[base + 2048  ] = bfu(h0.z) + bfu(l0.z);
            out_z[base + 3072  ] = bfu(h0.w) + bfu(l0.w);
            out_z[base + 4096  ] = bfu(h1.x) + bfu(l1.x);
            out_z[base + 5120  ] = bfu(h1.y) + bfu(l1.y);
            out_z[base + 6144  ] = bfu(h1.z) + bfu(l1.z);
            out_z[base + 7168  ] = bfu(h1.w) + bfu(l1.w);
        }
    }

    // ---- epilogue (wave-local): rows = pos quad*4+r, cols = code j*16+lcol ----
    float s1[4], s2[4]; int k1[4];
    #pragma unroll
    for (int r = 0; r < 4; ++r) { s1[r] = 1e30f; s2[r] = 1e30f; k1[r] = 511; }
    #pragma unroll
    for (int j = 0; j < 32; ++j) {
        int code = j * 16 + lcol;
        float wk = w2[code];
        #pragma unroll
        for (int r = 0; r < 4; ++r) {
            float s = wk - 2.f * acc[j][r];
            bmerge(s1[r], k1[r], s2[r], s, code, 1e30f);
        }
    }
    int akr[4];
    #pragma unroll
    for (int r = 0; r < 4; ++r) {
        float a1 = s1[r], a2 = s2[r]; int ak = k1[r];
        #pragma unroll
        for (int m = 1; m < 16; m <<= 1) {
            float o1 = __shfl_xor(a1, m);
            float o2 = __shfl_xor(a2, m);
            int   ok = __shfl_xor(ak, m);
            bmerge(a1, ak, a2, o1, ok, o2);
        }
        ak &= 511;
        akr[r] = ak;
        if (lcol == 0) {
            int pg = wp0 + quad * 4 + r;
            idx[pg] = ak;
            if (a2 - a1 < EPS_GAP) {
                int slot = atomicAdd(scnt, 1);
                if (slot < MAXSUS) spos[slot] = pg;
            }
        }
    }

    // ---- fused emb: lane = pos (lane&15), d-range quad*128..+128 ----
    const int p2 = lane & 15;
    const int quad2 = p2 >> 2, r2 = p2 & 3;
    int c0 = __shfl(akr[0], quad2 * 16);
    int c1 = __shfl(akr[1], quad2 * 16);
    int c2 = __shfl(akr[2], quad2 * 16);
    int c3 = __shfl(akr[3], quad2 * 16);
    int myc = (r2 == 0) ? c0 : (r2 == 1) ? c1 : (r2 == 2) ? c2 : c3;
    const float* row = cbT + (size_t)myc * 512;
    const size_t obase = ((size_t)b * 512) * 1024 + SP0 + p2;
    for (int d0 = quad * 128; d0 < quad * 128 + 128; d0 += 4) {
        if (skipTail && b == 31 && d0 >= 448) break;
        float4 v = *(const float4*)(row + d0);
        out_e[obase + (size_t)(d0    ) * 1024] = v.x;
        out_e[obase + (size_t)(d0 + 1) * 1024] = v.y;
        out_e[obase + (size_t)(d0 + 2) * 1024] = v.z;
        out_e[obase + (size_t)(d0 + 3) * 1024] = v.w;
    }
}

// ---------------------------------------------------------------------------
// Exact fp64 rescore of suspect positions; patches idx and emb column.
// ---------------------------------------------------------------------------
__global__ __launch_bounds__(256) void k_rescore(
        const float* __restrict__ out_z, const float* __restrict__ cbT,
        const double* __restrict__ w2d, int* __restrict__ idx,
        const int* __restrict__ scnt, const int* __restrict__ spos,
        float* __restrict__ out_e, int skipTail) {
    __shared__ float zsh[512];
    __shared__ float rs[256];
    __shared__ int rk[256];
    __shared__ int bc[2];
    const int t = threadIdx.x;
    int n = *scnt; if (n > MAXSUS) n = MAXSUS;
    for (int s = blockIdx.x; s < n; s += gridDim.x) {
        int p = spos[s] & 32767;
        int b = p >> 10, sp = p & 1023;
        __syncthreads();
        zsh[t]       = out_z[(size_t)(b * 512 + t) * 1024 + sp];
        zsh[t + 256] = out_z[(size_t)(b * 512 + t + 256) * 1024 + sp];
        __syncthreads();
        float bs = 1e30f; int bk = 511;
        for (int cc = 0; cc < 2; ++cc) {
            int k = t + cc * 256;
            double a = 0.0;
            const float* row = cbT + (size_t)k * 512;
            for (int d = 0; d < 512; ++d) a = fma((double)zsh[d], (double)row[d], a);
            float sc = (float)(w2d[k] - 2.0 * a);
            if (sc < bs || (sc == bs && k < bk)) { bs = sc; bk = k; }
        }
        rs[t] = bs; rk[t] = bk;
        __syncthreads();
        for (int str = 128; str > 0; str >>= 1) {
            if (t < str) {
                float so = rs[t + str]; int ko = rk[t + str];
                if (so < rs[t] || (so == rs[t] && ko < rk[t])) { rs[t] = so; rk[t] = ko; }
            }
            __syncthreads();
        }
        if (t == 0) {
            int kstar = rk[0] & 511;
            int old = idx[p] & 511;
            bc[0] = kstar; bc[1] = (kstar != old);
            idx[p] = kstar;
        }
        __syncthreads();
        if (bc[1]) {
            int kk = bc[0];
            for (int d = t; d < 512; d += 256) {
                if (skipTail && b == 31 && d >= 448) continue;
                out_e[(size_t)(b * 512 + d) * 1024 + sp] = cbT[(size_t)kk * 512 + d];
            }
        }
    }
}

// ---------------------------------------------------------------------------
__global__ __launch_bounds__(256) void k_recon(
        const float* __restrict__ U, const int* __restrict__ idx,
        float* __restrict__ out_r) {
    const int pos = blockIdx.x * 256 + threadIdx.x;
    const int id = idx[pos] & 511;
    const int b = pos >> 10, sp = pos & 1023, i = sp >> 5, j = sp & 31;
    const float* u = &U[(size_t)id * 48];
    #pragma unroll
    for (int c = 0; c < 3; ++c)
        #pragma unroll
        for (int uu = 0; uu < 4; ++uu) {
            float4 q = *(const float4*)(&u[c * 16 + uu * 4]);
            float4 o;
            o.x = 1.f / (1.f + __expf(-q.x));
            o.y = 1.f / (1.f + __expf(-q.y));
            o.z = 1.f / (1.f + __expf(-q.z));
            o.w = 1.f / (1.f + __expf(-q.w));
            *(float4*)(&out_r[((size_t)((b * 3 + c) * 128) + (i * 4 + uu)) * 128 + j * 4]) = o;
        }
}

// ---------------------------------------------------------------------------
__global__ __launch_bounds__(1024) void k_fixup(
        const void* __restrict__ cb, const int* __restrict__ flagp,
        const int* __restrict__ idx, float* __restrict__ out_e) {
    __shared__ int ii[1024];
    __shared__ int sflag;
    const int t = threadIdx.x;
    if (t == 0) sflag = *flagp;
    ii[t] = idx[31744 + t] & 511;
    __syncthreads();
    const int flag = sflag;
    for (int e = t; e < 65536; e += 1024) {
        int d = 448 + (e >> 10), sp = e & 1023;
        out_e[((size_t)(31 * 512 + d)) * 1024 + sp] = ldin(cb, (size_t)d * 512 + ii[sp], flag);
    }
}

// ---------------------------------------------------------------------------
extern "C" void kernel_launch(void* const* d_in, const int* in_sizes, int n_in,
                              void* d_out, int out_size, void* d_ws, size_t ws_size,
                              hipStream_t stream) {
    const void* x  = d_in[0];
    const void* We = d_in[1];
    const void* be = d_in[2];
    const void* Wd = d_in[3];
    const void* bd = d_in[4];
    const void* cb = d_in[5];

    float* out   = (float*)d_out;
    float* out_r = out;                       // 1,572,864 fp32 (6.29 MB)
    float* out_z = out + 1572864;             // 16,777,216 fp32
    float* out_e = out + 18350080;            // 16,777,216 fp32

    // Read-mostly tables in out_r (recon overwrites at the very end):
    char* Rb = (char*)out_r;
    float* cbF          = (float*)(Rb);                    // 1,048,576 B
    float* cbT          = (float*)(Rb + 1048576);          // 1,048,576 B
    float* cWe          = (float*)(Rb + 2097152);          //    98,304 B
    float* cbe          = (float*)(Rb + 2195456);          //     2,048 B
    float* cWd          = (float*)(Rb + 2197504);          //    98,304 B
    float* cbd          = (float*)(Rb + 2295808);          //        64 B
    unsigned short* cbHT= (unsigned short*)(Rb + 2295872); //   524,288 B
    unsigned short* cbLT= (unsigned short*)(Rb + 2820160); //   524,288 B

    // Tail scratch: prefer d_ws; else last 256 KB of out_e (fixup required).
    int tailWS = (ws_size >= 262144) ? 1 : 0;
    char* Tbase = tailWS ? (char*)d_ws : ((char*)out_e + 66846720);
    int skipTail = tailWS ? 0 : 1;
    int*    idx  = (int*)   (Tbase);            // 131,072 B
    float*  U    = (float*) (Tbase + 131072);   //  98,304 B
    float*  w2   = (float*) (Tbase + 229376);   //   2,048 B
    double* w2d  = (double*)(Tbase + 231424);   //   4,096 B
    int*    flag = (int*)   (Tbase + 235520);   //      64 B
    int*    scnt = (int*)   (Tbase + 235584);   //      64 B
    int*    spos = (int*)   (Tbase + 235648);   //  16,384 B

    k_sniff<<<1, 1024, 0, stream>>>(cb, flag, scnt);
    k_canonW<<<195, 256, 0, stream>>>(We, be, Wd, bd, flag, cWe, cbe, cWd, cbd);
    k_prepcb<<<dim3(8, 8), 256, 0, stream>>>(cb, flag, cbF, cbT, cbHT, cbLT);
    k_w2<<<8, 256, 0, stream>>>(cbF, w2, w2d);
    k_udec<<<128, 256, 0, stream>>>(cbT, cWd, cbd, U);

    k_main<<<512, 256, 0, stream>>>(x, cWe, cbe, flag, cbHT, cbLT, cbT, w2,
                                    out_z, out_e, idx, scnt, spos, skipTail);

    k_rescore<<<128, 256, 0, stream>>>(out_z, cbT, w2d, idx, scnt, spos, out_e, skipTail);
    k_recon<<<128, 256, 0, stream>>>(U, idx, out_r);
    if (skipTail)
        k_fixup<<<1, 1024, 0, stream>>>(cb, flag, idx, out_e);
}

// Round 3
// 378.454 us; speedup vs baseline: 1.2800x; 1.2800x over previous
//
#include <hip/hip_runtime.h>
#include <hip/hip_bf16.h>

// B=32, C=3, H=W=128, D=512, K=512, S=4, NPOS=32768
#define NPOS 32768
#define EPS_GAP 4e-3f
#define MAXSUS 4096

typedef __attribute__((ext_vector_type(8))) short short8;
typedef __attribute__((ext_vector_type(4))) float floatx4;

static __device__ __forceinline__ float bfu(unsigned short h) {
    return __uint_as_float(((unsigned int)h) << 16);
}
static __device__ __forceinline__ unsigned short f2bf(float f) {
    unsigned int u = __float_as_uint(f);
    u = (u + 0x7fffu + ((u >> 16) & 1u)) >> 16;   // RNE
    return (unsigned short)u;
}
static __device__ __forceinline__ float ldin(const void* p, size_t i, int flag) {
    return flag ? bfu(((const unsigned short*)p)[i]) : ((const float*)p)[i];
}

// LDS-only barrier: drains ds ops (lgkmcnt) but leaves global loads/stores
// in flight across the barrier (no vmcnt(0) drain — T4 principle).
static __device__ __forceinline__ void ldsbar() {
    asm volatile("s_waitcnt lgkmcnt(0)" ::: "memory");
    __builtin_amdgcn_s_barrier();
    asm volatile("" ::: "memory");
}

// ---------------------------------------------------------------------------
// Widened sniff: 1024 threads, 16-way d-split per column, LDS reduce.
// ---------------------------------------------------------------------------
__global__ __launch_bounds__(1024) void k_sniff(const void* __restrict__ cb,
                                                int* __restrict__ flag,
                                                int* __restrict__ scnt) {
    __shared__ float s[1024];
    const int t = threadIdx.x;
    const int k = t & 63, g = t >> 6;          // 16 groups x 32 d
    const unsigned short* u = (const unsigned short*)cb;
    float acc = 0.f;
    for (int d = g * 32; d < g * 32 + 32; ++d) {
        float v = bfu(u[(size_t)d * 512 + k]);
        acc = fmaf(v, v, acc);
    }
    s[t] = acc;
    __syncthreads();
    if (t < 64) {
        float a = 0.f;
        #pragma unroll
        for (int g2 = 0; g2 < 16; ++g2) a += s[g2 * 64 + k];
        int ok = (a >= 100.f && a <= 2000.f) ? 1 : 0;
        unsigned long long m = __ballot(ok);
        if (k == 0) {
            *flag = (m == ~0ull) ? 1 : 0;
            *scnt = 0;
        }
    }
}

// ---------------------------------------------------------------------------
__global__ void k_canonW(const void* __restrict__ We, const void* __restrict__ be,
                         const void* __restrict__ Wd, const void* __restrict__ bd,
                         const int* __restrict__ flagp, float* __restrict__ cWe,
                         float* __restrict__ cbe, float* __restrict__ cWd,
                         float* __restrict__ cbd) {
    int e = blockIdx.x * 256 + threadIdx.x;
    const int flag = *flagp;
    if (e < 24576)       cWe[e]         = ldin(We, e, flag);
    else if (e < 25088)  cbe[e - 24576] = ldin(be, e - 24576, flag);
    else if (e < 49664)  cWd[e - 25088] = ldin(Wd, e - 25088, flag);
    else if (e < 49667)  cbd[e - 49664] = ldin(bd, e - 49664, flag);
}

// ---------------------------------------------------------------------------
// cbF fp32 [d][k]; cbT fp32 [k][d]; cbHT/cbLT bf16-split [k][d].
// ---------------------------------------------------------------------------
__global__ __launch_bounds__(256) void k_prepcb(
        const void* __restrict__ cb, const int* __restrict__ flagp,
        float* __restrict__ cbF, float* __restrict__ cbT,
        unsigned short* __restrict__ cbHT, unsigned short* __restrict__ cbLT) {
    __shared__ float tile[64][65];
    const int flag = *flagp;
    const int D0 = blockIdx.x * 64, K0 = blockIdx.y * 64;
    const int t = threadIdx.x;
    for (int it = 0; it < 16; ++it) {
        int r = (t >> 6) + 4 * it, c = t & 63;
        float v = ldin(cb, (size_t)(D0 + r) * 512 + K0 + c, flag);
        cbF[(size_t)(D0 + r) * 512 + K0 + c] = v;
        tile[r][c] = v;
    }
    __syncthreads();
    for (int it = 0; it < 16; ++it) {
        int r = (t >> 6) + 4 * it, c = t & 63;
        float v = tile[c][r];
        size_t o = (size_t)(K0 + r) * 512 + D0 + c;
        cbT[o] = v;
        unsigned short h = f2bf(v);
        cbHT[o] = h;
        cbLT[o] = f2bf(v - bfu(h));
    }
}

// ---------------------------------------------------------------------------
// Widened w2: 256 threads/block, deterministic 4-way tree reduce.
// ---------------------------------------------------------------------------
__global__ __launch_bounds__(256) void k_w2(const float* __restrict__ cbF,
                                            float* __restrict__ w2,
                                            double* __restrict__ w2d) {
    __shared__ double s[256];
    const int t = threadIdx.x;
    const int k = blockIdx.x * 64 + (t & 63);
    const int g = t >> 6;                      // 4 groups x 128 d
    double acc = 0.0;
    for (int d = g * 128; d < g * 128 + 128; ++d) {
        double v = (double)cbF[(size_t)d * 512 + k];
        acc += v * v;
    }
    s[t] = acc;
    __syncthreads();
    if (t < 64) {
        double a = s[t] + s[t + 64] + s[t + 128] + s[t + 192];
        w2[k] = (float)a;
        w2d[k] = a;
    }
}

// ---------------------------------------------------------------------------
// U[k][c*16+u*4+v] = sum_d cbT[k][d]*cWd[c][d][3-u][3-v] + cbd[c]
// ---------------------------------------------------------------------------
__global__ __launch_bounds__(256) void k_udec(
        const float* __restrict__ cbT, const float* __restrict__ cWd,
        const float* __restrict__ cbd, float* __restrict__ U) {
    const int t = threadIdx.x;
    const int k = blockIdx.x * 4 + (t >> 6);
    const int lane = t & 63;
    const int j = lane >> 2, dpart = lane & 3;
    const int u = (j >> 2) & 3, v = j & 3;
    int woff[3];
    #pragma unroll
    for (int m = 0; m < 3; ++m) woff[m] = m * 8192 + (3 - u) * 4 + (3 - v);
    float a0 = 0.f, a1 = 0.f, a2 = 0.f;
    for (int i = 0; i < 128; ++i) {
        int d = dpart * 128 + i;
        float cw = cbT[(size_t)k * 512 + d];
        a0 = fmaf(cw, cWd[woff[0] + d * 16], a0);
        a1 = fmaf(cw, cWd[woff[1] + d * 16], a1);
        a2 = fmaf(cw, cWd[woff[2] + d * 16], a2);
    }
    a0 += __shfl_xor(a0, 1); a0 += __shfl_xor(a0, 2);
    a1 += __shfl_xor(a1, 1); a1 += __shfl_xor(a1, 2);
    a2 += __shfl_xor(a2, 1); a2 += __shfl_xor(a2, 2);
    if (dpart == 0) {
        U[k * 48 +  0 + j] = a0 + cbd[0];
        U[k * 48 + 16 + j] = a1 + cbd[1];
        U[k * 48 + 32 + j] = a2 + cbd[2];
    }
}

// ---------------------------------------------------------------------------
// k_main helpers (zq = pair base: zH = zq, zL = zq + 2560 shorts; rows 40 shorts)
// conv_step now ALSO writes out_z directly from registers (same value as old
// outz: bfu(h)+bfu(l)), so stores issue early and the outz LDS re-read is gone.
// ---------------------------------------------------------------------------
static __device__ __forceinline__ void conv_step(
        const float* __restrict__ patch, const float* __restrict__ cWe,
        const float* __restrict__ cbe, int dc, int t,
        unsigned short* __restrict__ zq,
        float* __restrict__ out_z, int b, int SP0) {
    const int cd = t & 31;
    const int ps = (t >> 5) * 8;
    const float4* wv = (const float4*)(cWe + (size_t)(dc + cd) * 48);
    const float bias = cbe[dc + cd];
    float za[8];
    #pragma unroll
    for (int p = 0; p < 8; ++p) za[p] = bias;
    #pragma unroll
    for (int q4 = 0; q4 < 12; ++q4) {
        float4 wq = wv[q4];
        #pragma unroll
        for (int p = 0; p < 8; ++p) {
            float4 v = ((const float4*)(patch + (ps + p) * 48))[q4];
            za[p] = fmaf(v.x, wq.x, za[p]);
            za[p] = fmaf(v.y, wq.y, za[p]);
            za[p] = fmaf(v.z, wq.z, za[p]);
            za[p] = fmaf(v.w, wq.w, za[p]);
        }
    }
    float zf[8];
    #pragma unroll
    for (int p = 0; p < 8; ++p) {
        float z = fmaxf(za[p], 0.f);
        unsigned short h = f2bf(z);
        unsigned short l = f2bf(z - bfu(h));
        zq[(ps + p) * 40 + cd] = h;
        zq[2560 + (ps + p) * 40 + cd] = l;
        zf[p] = bfu(h) + bfu(l);
    }
    // out_z[b][dc+cd][SP0+ps .. +8]: 32B contiguous per lane, 2x dwordx4
    size_t zbase = (size_t)(b * 512 + dc + cd) * 1024 + SP0 + ps;
    *(float4*)(out_z + zbase)     = (float4){zf[0], zf[1], zf[2], zf[3]};
    *(float4*)(out_z + zbase + 4) = (float4){zf[4], zf[5], zf[6], zf[7]};
}

static __device__ __forceinline__ void mfma_step(
        const unsigned short* __restrict__ zq,
        const unsigned short* __restrict__ cbHT,
        const unsigned short* __restrict__ cbLT,
        int dcPrev, int wave, int quad, int lcol, int flag, floatx4 (&acc)[4][8]) {
    short8 aH[4], aL[4];
    #pragma unroll
    for (int mt = 0; mt < 4; ++mt) {
        aH[mt] = *(const short8*)(zq + (mt * 16 + lcol) * 40 + quad * 8);
        aL[mt] = *(const short8*)(zq + 2560 + (mt * 16 + lcol) * 40 + quad * 8);
    }
    #pragma unroll
    for (int j = 0; j < 8; ++j) {
        int code = (wave * 8 + j) * 16 + lcol;
        short8 bH = *(const short8*)(cbHT + (size_t)code * 512 + dcPrev + quad * 8);
        #pragma unroll
        for (int mt = 0; mt < 4; ++mt) {
            acc[mt][j] = __builtin_amdgcn_mfma_f32_16x16x32_bf16(aH[mt], bH, acc[mt][j], 0, 0, 0);
            acc[mt][j] = __builtin_amdgcn_mfma_f32_16x16x32_bf16(aL[mt], bH, acc[mt][j], 0, 0, 0);
        }
    }
    if (!flag) {   // fp32 inputs: third term zh*cbL
        #pragma unroll
        for (int j = 0; j < 8; ++j) {
            int code = (wave * 8 + j) * 16 + lcol;
            short8 bL = *(const short8*)(cbLT + (size_t)code * 512 + dcPrev + quad * 8);
            #pragma unroll
            for (int mt = 0; mt < 4; ++mt)
                acc[mt][j] = __builtin_amdgcn_mfma_f32_16x16x32_bf16(aH[mt], bL, acc[mt][j], 0, 0, 0);
        }
    }
}

// best/second combine: (a1,ak,a2) <- merge (o1,ok,o2)
static __device__ __forceinline__ void bmerge(float& a1, int& ak, float& a2,
                                              float o1, int ok, float o2) {
    if (o1 < a1)      { a2 = fminf(a1, o2); a1 = o1; ak = ok; }
    else if (o1 > a1) { a2 = fminf(a2, o1); }
    else              { a2 = a1; if (ok < ak) ak = ok; }   // exact tie -> gap 0 (suspect)
}

// ---------------------------------------------------------------------------
// FUSED main v6 = v3 structure + LDS-only barriers (no vmcnt drain) + out_z
// stores fused into conv (register -> global, issued early each phase).
//   iter dc: ldsbar; conv(dc)->buf p (+out_z stores); mfma(dc-32)<-buf 1-p.
// LDS: patch 12288 | z pairs 2x10240 = 32768 B total.
// ---------------------------------------------------------------------------
__global__ __launch_bounds__(256, 2) void k_main(
        const void* __restrict__ x, const float* __restrict__ cWe,
        const float* __restrict__ cbe, const int* __restrict__ flagp,
        const unsigned short* __restrict__ cbHT, const unsigned short* __restrict__ cbLT,
        const float* __restrict__ cbT, const float* __restrict__ w2,
        float* __restrict__ out_z, float* __restrict__ out_e,
        int* __restrict__ idx, int* __restrict__ scnt, int* __restrict__ spos,
        int skipTail) {
    __shared__ __align__(16) char smc[32768];
    float* patch = (float*)smc;                               // [64][48] fp32
    unsigned short* zb = (unsigned short*)(smc + 12288);      // 2 pairs x 5120 shorts

    const int t = threadIdx.x;
    const int P0 = blockIdx.x * 64;
    const int b = P0 >> 10, SP0 = P0 & 1023;
    const int flag = *flagp;
    const int wave = t >> 6, lane = t & 63;
    const int quad = lane >> 4, lcol = lane & 15;

    // stage x patches once
    for (int e = t; e < 3072; e += 256) {
        int pid = e / 48, kk = e % 48;
        int c = kk >> 4, r = (kk >> 2) & 3, s = kk & 3;
        int pos = P0 + pid;
        int bb = pos >> 10, sp = pos & 1023, i = sp >> 5, j = sp & 31;
        patch[pid * 48 + kk] = ldin(x, ((bb * 3 + c) * 128 + (i * 4 + r)) * 128 + (j * 4 + s), flag);
    }

    floatx4 acc[4][8];
    #pragma unroll
    for (int mt = 0; mt < 4; ++mt)
        #pragma unroll
        for (int j = 0; j < 8; ++j) acc[mt][j] = (floatx4){0.f, 0.f, 0.f, 0.f};

    ldsbar();
    conv_step(patch, cWe, cbe, 0, t, zb, out_z, b, SP0);      // chunk 0 -> pair 0
    for (int dc = 32; dc < 512; dc += 32) {
        ldsbar();
        const int p = (dc >> 5) & 1;
        conv_step(patch, cWe, cbe, dc, t, zb + p * 5120, out_z, b, SP0);
        mfma_step(zb + (p ^ 1) * 5120, cbHT, cbLT, dc - 32, wave, quad, lcol, flag, acc);
    }
    ldsbar();
    mfma_step(zb + 5120, cbHT, cbLT, 480, wave, quad, lcol, flag, acc);

    // ---- epilogue: per-lane best/second over its 8 codes, then shuffle ----
    float s1[4][4], s2[4][4]; int k1[4][4];
    #pragma unroll
    for (int mt = 0; mt < 4; ++mt)
        #pragma unroll
        for (int r = 0; r < 4; ++r) { s1[mt][r] = 1e30f; s2[mt][r] = 1e30f; k1[mt][r] = 511; }
    #pragma unroll
    for (int j = 0; j < 8; ++j) {
        int code = (wave * 8 + j) * 16 + lcol;
        float wk = w2[code];
        #pragma unroll
        for (int mt = 0; mt < 4; ++mt)
            #pragma unroll
            for (int r = 0; r < 4; ++r) {
                float s = wk - 2.f * acc[mt][j][r];
                bmerge(s1[mt][r], k1[mt][r], s2[mt][r], s, code, 1e30f);
            }
    }
    // overlay reduction arrays on patch region (patch dead after last conv+bar)
    float* sS1 = (float*)smc;             // [64 pos][4 wave]
    int*   sK1 = (int*)(smc + 1024);
    float* sS2 = (float*)(smc + 2048);
    int*   ii  = (int*)(smc + 3072);      // [64]
    #pragma unroll
    for (int mt = 0; mt < 4; ++mt)
        #pragma unroll
        for (int r = 0; r < 4; ++r) {
            float a1 = s1[mt][r], a2 = s2[mt][r]; int ak = k1[mt][r];
            #pragma unroll
            for (int m = 1; m < 16; m <<= 1) {
                float o1 = __shfl_xor(a1, m);
                float o2 = __shfl_xor(a2, m);
                int   ok = __shfl_xor(ak, m);
                bmerge(a1, ak, a2, o1, ok, o2);
            }
            if (lcol == 0) {
                int pos = mt * 16 + quad * 4 + r;
                sS1[pos * 4 + wave] = a1;
                sK1[pos * 4 + wave] = ak;
                sS2[pos * 4 + wave] = a2;
            }
        }
    __syncthreads();
    if (t < 64) {
        float a1 = sS1[t * 4]; int ak = sK1[t * 4]; float a2 = sS2[t * 4];
        #pragma unroll
        for (int w = 1; w < 4; ++w)
            bmerge(a1, ak, a2, sS1[t * 4 + w], sK1[t * 4 + w], sS2[t * 4 + w]);
        ak &= 511;
        ii[t] = ak;
        idx[P0 + t] = ak;
        if (a2 - a1 < EPS_GAP) {
            int slot = atomicAdd(scnt, 1);
            if (slot < MAXSUS) spos[slot] = P0 + t;
        }
    }
    __syncthreads();

    // ---- fused emb: out_e[b][d][SP0+sp] = cbT[ii[sp]][d] ----
    const int sp = t & 63, dq = t >> 6;
    const float* row = cbT + (size_t)ii[sp] * 512;
    const size_t obase = ((size_t)b * 512) * 1024 + SP0 + sp;
    for (int d0 = dq * 128; d0 < dq * 128 + 128; d0 += 4) {
        if (skipTail && b == 31 && d0 >= 448) break;
        float4 v = *(const float4*)(row + d0);
        out_e[obase + (size_t)(d0    ) * 1024] = v.x;
        out_e[obase + (size_t)(d0 + 1) * 1024] = v.y;
        out_e[obase + (size_t)(d0 + 2) * 1024] = v.z;
        out_e[obase + (size_t)(d0 + 3) * 1024] = v.w;
    }
}

// ---------------------------------------------------------------------------
// Exact fp64 rescore of suspect positions; patches idx and emb column.
// ---------------------------------------------------------------------------
__global__ __launch_bounds__(256) void k_rescore(
        const float* __restrict__ out_z, const float* __restrict__ cbT,
        const double* __restrict__ w2d, int* __restrict__ idx,
        const int* __restrict__ scnt, const int* __restrict__ spos,
        float* __restrict__ out_e, int skipTail) {
    __shared__ float zsh[512];
    __shared__ float rs[256];
    __shared__ int rk[256];
    __shared__ int bc[2];
    const int t = threadIdx.x;
    int n = *scnt; if (n > MAXSUS) n = MAXSUS;
    for (int s = blockIdx.x; s < n; s += gridDim.x) {
        int p = spos[s] & 32767;
        int b = p >> 10, sp = p & 1023;
        __syncthreads();
        zsh[t]       = out_z[(size_t)(b * 512 + t) * 1024 + sp];
        zsh[t + 256] = out_z[(size_t)(b * 512 + t + 256) * 1024 + sp];
        __syncthreads();
        float bs = 1e30f; int bk = 511;
        for (int cc = 0; cc < 2; ++cc) {
            int k = t + cc * 256;
            double a = 0.0;
            const float* row = cbT + (size_t)k * 512;
            for (int d = 0; d < 512; ++d) a = fma((double)zsh[d], (double)row[d], a);
            float sc = (float)(w2d[k] - 2.0 * a);
            if (sc < bs || (sc == bs && k < bk)) { bs = sc; bk = k; }
        }
        rs[t] = bs; rk[t] = bk;
        __syncthreads();
        for (int str = 128; str > 0; str >>= 1) {
            if (t < str) {
                float so = rs[t + str]; int ko = rk[t + str];
                if (so < rs[t] || (so == rs[t] && ko < rk[t])) { rs[t] = so; rk[t] = ko; }
            }
            __syncthreads();
        }
        if (t == 0) {
            int kstar = rk[0] & 511;
            int old = idx[p] & 511;
            bc[0] = kstar; bc[1] = (kstar != old);
            idx[p] = kstar;
        }
        __syncthreads();
        if (bc[1]) {
            int kk = bc[0];
            for (int d = t; d < 512; d += 256) {
                if (skipTail && b == 31 && d >= 448) continue;
                out_e[(size_t)(b * 512 + d) * 1024 + sp] = cbT[(size_t)kk * 512 + d];
            }
        }
    }
}

// ---------------------------------------------------------------------------
__global__ __launch_bounds__(256) void k_recon(
        const float* __restrict__ U, const int* __restrict__ idx,
        float* __restrict__ out_r) {
    const int pos = blockIdx.x * 256 + threadIdx.x;
    const int id = idx[pos] & 511;
    const int b = pos >> 10, sp = pos & 1023, i = sp >> 5, j = sp & 31;
    const float* u = &U[(size_t)id * 48];
    #pragma unroll
    for (int c = 0; c < 3; ++c)
        #pragma unroll
        for (int uu = 0; uu < 4; ++uu) {
            float4 q = *(const float4*)(&u[c * 16 + uu * 4]);
            float4 o;
            o.x = 1.f / (1.f + __expf(-q.x));
            o.y = 1.f / (1.f + __expf(-q.y));
            o.z = 1.f / (1.f + __expf(-q.z));
            o.w = 1.f / (1.f + __expf(-q.w));
            *(float4*)(&out_r[((size_t)((b * 3 + c) * 128) + (i * 4 + uu)) * 128 + j * 4]) = o;
        }
}

// ---------------------------------------------------------------------------
__global__ __launch_bounds__(1024) void k_fixup(
        const void* __restrict__ cb, const int* __restrict__ flagp,
        const int* __restrict__ idx, float* __restrict__ out_e) {
    __shared__ int ii[1024];
    __shared__ int sflag;
    const int t = threadIdx.x;
    if (t == 0) sflag = *flagp;
    ii[t] = idx[31744 + t] & 511;
    __syncthreads();
    const int flag = sflag;
    for (int e = t; e < 65536; e += 1024) {
        int d = 448 + (e >> 10), sp = e & 1023;
        out_e[((size_t)(31 * 512 + d)) * 1024 + sp] = ldin(cb, (size_t)d * 512 + ii[sp], flag);
    }
}

// ---------------------------------------------------------------------------
extern "C" void kernel_launch(void* const* d_in, const int* in_sizes, int n_in,
                              void* d_out, int out_size, void* d_ws, size_t ws_size,
                              hipStream_t stream) {
    const void* x  = d_in[0];
    const void* We = d_in[1];
    const void* be = d_in[2];
    const void* Wd = d_in[3];
    const void* bd = d_in[4];
    const void* cb = d_in[5];

    float* out   = (float*)d_out;
    float* out_r = out;                       // 1,572,864 fp32 (6.29 MB)
    float* out_z = out + 1572864;             // 16,777,216 fp32
    float* out_e = out + 18350080;            // 16,777,216 fp32

    // Read-mostly tables in out_r (recon overwrites at the very end):
    char* Rb = (char*)out_r;
    float* cbF          = (float*)(Rb);                    // 1,048,576 B
    float* cbT          = (float*)(Rb + 1048576);          // 1,048,576 B
    float* cWe          = (float*)(Rb + 2097152);          //    98,304 B
    float* cbe          = (float*)(Rb + 2195456);          //     2,048 B
    float* cWd          = (float*)(Rb + 2197504);          //    98,304 B
    float* cbd          = (float*)(Rb + 2295808);          //        64 B
    unsigned short* cbHT= (unsigned short*)(Rb + 2295872); //   524,288 B
    unsigned short* cbLT= (unsigned short*)(Rb + 2820160); //   524,288 B

    // Tail scratch: prefer d_ws; else last 256 KB of out_e (fixup required).
    int tailWS = (ws_size >= 262144) ? 1 : 0;
    char* Tbase = tailWS ? (char*)d_ws : ((char*)out_e + 66846720);
    int skipTail = tailWS ? 0 : 1;
    int*    idx  = (int*)   (Tbase);            // 131,072 B
    float*  U    = (float*) (Tbase + 131072);   //  98,304 B
    float*  w2   = (float*) (Tbase + 229376);   //   2,048 B
    double* w2d  = (double*)(Tbase + 231424);   //   4,096 B
    int*    flag = (int*)   (Tbase + 235520);   //      64 B
    int*    scnt = (int*)   (Tbase + 235584);   //      64 B
    int*    spos = (int*)   (Tbase + 235648);   //  16,384 B

    k_sniff<<<1, 1024, 0, stream>>>(cb, flag, scnt);
    k_canonW<<<195, 256, 0, stream>>>(We, be, Wd, bd, flag, cWe, cbe, cWd, cbd);
    k_prepcb<<<dim3(8, 8), 256, 0, stream>>>(cb, flag, cbF, cbT, cbHT, cbLT);
    k_w2<<<8, 256, 0, stream>>>(cbF, w2, w2d);
    k_udec<<<128, 256, 0, stream>>>(cbT, cWd, cbd, U);

    k_main<<<512, 256, 0, stream>>>(x, cWe, cbe, flag, cbHT, cbLT, cbT, w2,
                                    out_z, out_e, idx, scnt, spos, skipTail);

    k_rescore<<<128, 256, 0, stream>>>(out_z, cbT, w2d, idx, scnt, spos, out_e, skipTail);
    k_recon<<<128, 256, 0, stream>>>(U, idx, out_r);
    if (skipTail)
        k_fixup<<<1, 1024, 0, stream>>>(cb, flag, idx, out_e);
}

// Round 5
// 338.570 us; speedup vs baseline: 1.4307x; 1.1178x over previous
//
#include <hip/hip_runtime.h>
#include <hip/hip_bf16.h>

// B=32, C=3, H=W=128, D=512, K=512, S=4, NPOS=32768
#define NPOS 32768
#define EPS_GAP 4e-3f
#define MAXSUS 4096

typedef __attribute__((ext_vector_type(8))) short short8;
typedef __attribute__((ext_vector_type(4))) float floatx4;

static __device__ __forceinline__ float bfu(unsigned short h) {
    return __uint_as_float(((unsigned int)h) << 16);
}
static __device__ __forceinline__ unsigned short f2bf(float f) {
    unsigned int u = __float_as_uint(f);
    u = (u + 0x7fffu + ((u >> 16) & 1u)) >> 16;   // RNE
    return (unsigned short)u;
}
static __device__ __forceinline__ float ldin(const void* p, size_t i, int flag) {
    return flag ? bfu(((const unsigned short*)p)[i]) : ((const float*)p)[i];
}

// LDS-only barrier: drains ds ops (lgkmcnt) but leaves global loads/stores
// in flight across the barrier (no vmcnt(0) drain).
static __device__ __forceinline__ void ldsbar() {
    asm volatile("s_waitcnt lgkmcnt(0)" ::: "memory");
    __builtin_amdgcn_s_barrier();
    asm volatile("" ::: "memory");
}

// ---------------------------------------------------------------------------
// Sniff: decide bf16 vs fp32 input encoding from codebook column norms.
// ---------------------------------------------------------------------------
__global__ __launch_bounds__(1024) void k_sniff(const void* __restrict__ cb,
                                                int* __restrict__ flag,
                                                int* __restrict__ scnt) {
    __shared__ float s[1024];
    const int t = threadIdx.x;
    const int k = t & 63, g = t >> 6;          // 16 groups x 32 d
    const unsigned short* u = (const unsigned short*)cb;
    float acc = 0.f;
    for (int d = g * 32; d < g * 32 + 32; ++d) {
        float v = bfu(u[(size_t)d * 512 + k]);
        acc = fmaf(v, v, acc);
    }
    s[t] = acc;
    __syncthreads();
    if (t < 64) {
        float a = 0.f;
        #pragma unroll
        for (int g2 = 0; g2 < 16; ++g2) a += s[g2 * 64 + k];
        int ok = (a >= 100.f && a <= 2000.f) ? 1 : 0;
        unsigned long long m = __ballot(ok);
        if (k == 0) {
            *flag = (m == ~0ull) ? 1 : 0;
            *scnt = 0;
        }
    }
}

// ---------------------------------------------------------------------------
// FUSED prep: one launch, role-split by blockIdx. NO cross-role dependencies:
//   bid   0..194 : canonW  (copy We/be/Wd/bd -> canonical fp32)   [reads raw]
//   bid 195..258 : prepcb  (cb -> cbT fp32 [k][d], cbHT/cbLT bf16) [reads raw cb]
//   bid 259..266 : w2      (column norms, fp32+fp64)               [reads raw cb]
//   bid 267..394 : udec    (decoder LUT U[k][48])                  [reads raw cb/Wd/bd]
// udec MUST read Wd/bd raw (not cWd/cbd): those are written by canonW blocks
// of this same launch — no inter-block ordering exists (round-4 bug).
// Values are bitwise-identical (canonW is a verbatim element copy).
// ---------------------------------------------------------------------------
__global__ __launch_bounds__(256) void k_prepAll(
        const void* __restrict__ We, const void* __restrict__ be,
        const void* __restrict__ Wd, const void* __restrict__ bd,
        const void* __restrict__ cb, const int* __restrict__ flagp,
        float* __restrict__ cWe, float* __restrict__ cbe,
        float* __restrict__ cWd, float* __restrict__ cbd,
        float* __restrict__ cbT, unsigned short* __restrict__ cbHT,
        unsigned short* __restrict__ cbLT,
        float* __restrict__ w2, double* __restrict__ w2d,
        float* __restrict__ U) {
    __shared__ float tile[64][65];
    __shared__ double sd[256];
    const int bid = blockIdx.x;
    const int t = threadIdx.x;
    const int flag = *flagp;

    if (bid < 195) {
        // ---- canonW ----
        int e = bid * 256 + t;
        if (e < 24576)       cWe[e]         = ldin(We, e, flag);
        else if (e < 25088)  cbe[e - 24576] = ldin(be, e - 24576, flag);
        else if (e < 49664)  cWd[e - 25088] = ldin(Wd, e - 25088, flag);
        else if (e < 49667)  cbd[e - 49664] = ldin(bd, e - 49664, flag);
    } else if (bid < 259) {
        // ---- prepcb ----
        const int bb = bid - 195;
        const int D0 = (bb >> 3) * 64, K0 = (bb & 7) * 64;
        for (int it = 0; it < 16; ++it) {
            int r = (t >> 6) + 4 * it, c = t & 63;
            tile[r][c] = ldin(cb, (size_t)(D0 + r) * 512 + K0 + c, flag);
        }
        __syncthreads();
        for (int it = 0; it < 16; ++it) {
            int r = (t >> 6) + 4 * it, c = t & 63;
            float v = tile[c][r];
            size_t o = (size_t)(K0 + r) * 512 + D0 + c;
            cbT[o] = v;
            unsigned short h = f2bf(v);
            cbHT[o] = h;
            cbLT[o] = f2bf(v - bfu(h));
        }
    } else if (bid < 267) {
        // ---- w2 ----
        const int k = (bid - 259) * 64 + (t & 63);
        const int g = t >> 6;                  // 4 groups x 128 d
        double acc = 0.0;
        for (int d = g * 128; d < g * 128 + 128; ++d) {
            double v = (double)ldin(cb, (size_t)d * 512 + k, flag);
            acc += v * v;
        }
        sd[t] = acc;
        __syncthreads();
        if (t < 64) {
            double a = sd[t] + sd[t + 64] + sd[t + 128] + sd[t + 192];
            w2[k] = (float)a;
            w2d[k] = a;
        }
    } else {
        // ---- udec: U[k][c*16+u*4+v] = sum_d cb[d][k]*Wd[c][d][3-u][3-v]+bd[c]
        const int kk = (bid - 267) * 4 + (t >> 6);
        const int lane = t & 63;
        const int j = lane >> 2, dpart = lane & 3;
        const int u = (j >> 2) & 3, v = j & 3;
        int woff[3];
        #pragma unroll
        for (int m = 0; m < 3; ++m) woff[m] = m * 8192 + (3 - u) * 4 + (3 - v);
        float a0 = 0.f, a1 = 0.f, a2 = 0.f;
        for (int i = 0; i < 128; ++i) {
            int d = dpart * 128 + i;
            float cw = ldin(cb, (size_t)d * 512 + kk, flag);
            a0 = fmaf(cw, ldin(Wd, (size_t)(woff[0] + d * 16), flag), a0);
            a1 = fmaf(cw, ldin(Wd, (size_t)(woff[1] + d * 16), flag), a1);
            a2 = fmaf(cw, ldin(Wd, (size_t)(woff[2] + d * 16), flag), a2);
        }
        a0 += __shfl_xor(a0, 1); a0 += __shfl_xor(a0, 2);
        a1 += __shfl_xor(a1, 1); a1 += __shfl_xor(a1, 2);
        a2 += __shfl_xor(a2, 1); a2 += __shfl_xor(a2, 2);
        if (dpart == 0) {
            U[kk * 48 +  0 + j] = a0 + ldin(bd, 0, flag);
            U[kk * 48 + 16 + j] = a1 + ldin(bd, 1, flag);
            U[kk * 48 + 32 + j] = a2 + ldin(bd, 2, flag);
        }
    }
}

// ---------------------------------------------------------------------------
// k_main helpers (zq = pair base: zH = zq, zL = zq + 2560 shorts; rows 40 shorts)
// conv_step writes out_z directly from registers.
// ---------------------------------------------------------------------------
static __device__ __forceinline__ void conv_step(
        const float* __restrict__ patch, const float* __restrict__ cWe,
        const float* __restrict__ cbe, int dc, int t,
        unsigned short* __restrict__ zq,
        float* __restrict__ out_z, int b, int SP0) {
    const int cd = t & 31;
    const int ps = (t >> 5) * 8;
    const float4* wv = (const float4*)(cWe + (size_t)(dc + cd) * 48);
    const float bias = cbe[dc + cd];
    float za[8];
    #pragma unroll
    for (int p = 0; p < 8; ++p) za[p] = bias;
    #pragma unroll
    for (int q4 = 0; q4 < 12; ++q4) {
        float4 wq = wv[q4];
        #pragma unroll
        for (int p = 0; p < 8; ++p) {
            float4 v = ((const float4*)(patch + (ps + p) * 48))[q4];
            za[p] = fmaf(v.x, wq.x, za[p]);
            za[p] = fmaf(v.y, wq.y, za[p]);
            za[p] = fmaf(v.z, wq.z, za[p]);
            za[p] = fmaf(v.w, wq.w, za[p]);
        }
    }
    float zf[8];
    #pragma unroll
    for (int p = 0; p < 8; ++p) {
        float z = fmaxf(za[p], 0.f);
        unsigned short h = f2bf(z);
        unsigned short l = f2bf(z - bfu(h));
        zq[(ps + p) * 40 + cd] = h;
        zq[2560 + (ps + p) * 40 + cd] = l;
        zf[p] = bfu(h) + bfu(l);
    }
    size_t zbase = (size_t)(b * 512 + dc + cd) * 1024 + SP0 + ps;
    *(float4*)(out_z + zbase)     = (float4){zf[0], zf[1], zf[2], zf[3]};
    *(float4*)(out_z + zbase + 4) = (float4){zf[4], zf[5], zf[6], zf[7]};
}

static __device__ __forceinline__ void mfma_step(
        const unsigned short* __restrict__ zq,
        const unsigned short* __restrict__ cbHT,
        const unsigned short* __restrict__ cbLT,
        int dcPrev, int wave, int quad, int lcol, int flag, floatx4 (&acc)[4][8]) {
    short8 aH[4], aL[4];
    #pragma unroll
    for (int mt = 0; mt < 4; ++mt) {
        aH[mt] = *(const short8*)(zq + (mt * 16 + lcol) * 40 + quad * 8);
        aL[mt] = *(const short8*)(zq + 2560 + (mt * 16 + lcol) * 40 + quad * 8);
    }
    #pragma unroll
    for (int j = 0; j < 8; ++j) {
        int code = (wave * 8 + j) * 16 + lcol;
        short8 bH = *(const short8*)(cbHT + (size_t)code * 512 + dcPrev + quad * 8);
        #pragma unroll
        for (int mt = 0; mt < 4; ++mt) {
            acc[mt][j] = __builtin_amdgcn_mfma_f32_16x16x32_bf16(aH[mt], bH, acc[mt][j], 0, 0, 0);
            acc[mt][j] = __builtin_amdgcn_mfma_f32_16x16x32_bf16(aL[mt], bH, acc[mt][j], 0, 0, 0);
        }
    }
    if (!flag) {   // fp32 inputs: third term zh*cbL
        #pragma unroll
        for (int j = 0; j < 8; ++j) {
            int code = (wave * 8 + j) * 16 + lcol;
            short8 bL = *(const short8*)(cbLT + (size_t)code * 512 + dcPrev + quad * 8);
            #pragma unroll
            for (int mt = 0; mt < 4; ++mt)
                acc[mt][j] = __builtin_amdgcn_mfma_f32_16x16x32_bf16(aH[mt], bL, acc[mt][j], 0, 0, 0);
        }
    }
}

// best/second combine: (a1,ak,a2) <- merge (o1,ok,o2)
static __device__ __forceinline__ void bmerge(float& a1, int& ak, float& a2,
                                              float o1, int ok, float o2) {
    if (o1 < a1)      { a2 = fminf(a1, o2); a1 = o1; ak = ok; }
    else if (o1 > a1) { a2 = fminf(a2, o1); }
    else              { a2 = a1; if (ok < ak) ak = ok; }   // exact tie -> gap 0 (suspect)
}

// ---------------------------------------------------------------------------
// FUSED main v7 = v6 verbatim, except suspect positions are tagged via the
// SIGN BIT of idx[] so k_post's recon role can skip them (no ordering needed).
// ---------------------------------------------------------------------------
__global__ __launch_bounds__(256, 2) void k_main(
        const void* __restrict__ x, const float* __restrict__ cWe,
        const float* __restrict__ cbe, const int* __restrict__ flagp,
        const unsigned short* __restrict__ cbHT, const unsigned short* __restrict__ cbLT,
        const float* __restrict__ cbT, const float* __restrict__ w2,
        float* __restrict__ out_z, float* __restrict__ out_e,
        int* __restrict__ idx, int* __restrict__ scnt, int* __restrict__ spos,
        int skipTail) {
    __shared__ __align__(16) char smc[32768];
    float* patch = (float*)smc;                               // [64][48] fp32
    unsigned short* zb = (unsigned short*)(smc + 12288);      // 2 pairs x 5120 shorts

    const int t = threadIdx.x;
    const int P0 = blockIdx.x * 64;
    const int b = P0 >> 10, SP0 = P0 & 1023;
    const int flag = *flagp;
    const int wave = t >> 6, lane = t & 63;
    const int quad = lane >> 4, lcol = lane & 15;

    // stage x patches once
    for (int e = t; e < 3072; e += 256) {
        int pid = e / 48, kk = e % 48;
        int c = kk >> 4, r = (kk >> 2) & 3, s = kk & 3;
        int pos = P0 + pid;
        int bb = pos >> 10, sp = pos & 1023, i = sp >> 5, j = sp & 31;
        patch[pid * 48 + kk] = ldin(x, ((bb * 3 + c) * 128 + (i * 4 + r)) * 128 + (j * 4 + s), flag);
    }

    floatx4 acc[4][8];
    #pragma unroll
    for (int mt = 0; mt < 4; ++mt)
        #pragma unroll
        for (int j = 0; j < 8; ++j) acc[mt][j] = (floatx4){0.f, 0.f, 0.f, 0.f};

    ldsbar();
    conv_step(patch, cWe, cbe, 0, t, zb, out_z, b, SP0);      // chunk 0 -> pair 0
    for (int dc = 32; dc < 512; dc += 32) {
        ldsbar();
        const int p = (dc >> 5) & 1;
        conv_step(patch, cWe, cbe, dc, t, zb + p * 5120, out_z, b, SP0);
        mfma_step(zb + (p ^ 1) * 5120, cbHT, cbLT, dc - 32, wave, quad, lcol, flag, acc);
    }
    ldsbar();
    mfma_step(zb + 5120, cbHT, cbLT, 480, wave, quad, lcol, flag, acc);

    // ---- epilogue: per-lane best/second over its 8 codes, then shuffle ----
    float s1[4][4], s2[4][4]; int k1[4][4];
    #pragma unroll
    for (int mt = 0; mt < 4; ++mt)
        #pragma unroll
        for (int r = 0; r < 4; ++r) { s1[mt][r] = 1e30f; s2[mt][r] = 1e30f; k1[mt][r] = 511; }
    #pragma unroll
    for (int j = 0; j < 8; ++j) {
        int code = (wave * 8 + j) * 16 + lcol;
        float wk = w2[code];
        #pragma unroll
        for (int mt = 0; mt < 4; ++mt)
            #pragma unroll
            for (int r = 0; r < 4; ++r) {
                float s = wk - 2.f * acc[mt][j][r];
                bmerge(s1[mt][r], k1[mt][r], s2[mt][r], s, code, 1e30f);
            }
    }
    // overlay reduction arrays on patch region (patch dead after last conv+bar)
    float* sS1 = (float*)smc;             // [64 pos][4 wave]
    int*   sK1 = (int*)(smc + 1024);
    float* sS2 = (float*)(smc + 2048);
    int*   ii  = (int*)(smc + 3072);      // [64]
    #pragma unroll
    for (int mt = 0; mt < 4; ++mt)
        #pragma unroll
        for (int r = 0; r < 4; ++r) {
            float a1 = s1[mt][r], a2 = s2[mt][r]; int ak = k1[mt][r];
            #pragma unroll
            for (int m = 1; m < 16; m <<= 1) {
                float o1 = __shfl_xor(a1, m);
                float o2 = __shfl_xor(a2, m);
                int   ok = __shfl_xor(ak, m);
                bmerge(a1, ak, a2, o1, ok, o2);
            }
            if (lcol == 0) {
                int pos = mt * 16 + quad * 4 + r;
                sS1[pos * 4 + wave] = a1;
                sK1[pos * 4 + wave] = ak;
                sS2[pos * 4 + wave] = a2;
            }
        }
    __syncthreads();
    if (t < 64) {
        float a1 = sS1[t * 4]; int ak = sK1[t * 4]; float a2 = sS2[t * 4];
        #pragma unroll
        for (int w = 1; w < 4; ++w)
            bmerge(a1, ak, a2, sS1[t * 4 + w], sK1[t * 4 + w], sS2[t * 4 + w]);
        ak &= 511;
        ii[t] = ak;
        unsigned int flagged = 0u;
        if (a2 - a1 < EPS_GAP) {
            int slot = atomicAdd(scnt, 1);
            if (slot < MAXSUS) { spos[slot] = P0 + t; flagged = 1u; }
        }
        idx[P0 + t] = (int)((unsigned)ak | (flagged << 31));
    }
    __syncthreads();

    // ---- fused emb: out_e[b][d][SP0+sp] = cbT[ii[sp]][d] ----
    const int sp = t & 63, dq = t >> 6;
    const float* row = cbT + (size_t)ii[sp] * 512;
    const size_t obase = ((size_t)b * 512) * 1024 + SP0 + sp;
    for (int d0 = dq * 128; d0 < dq * 128 + 128; d0 += 4) {
        if (skipTail && b == 31 && d0 >= 448) break;
        float4 v = *(const float4*)(row + d0);
        out_e[obase + (size_t)(d0    ) * 1024] = v.x;
        out_e[obase + (size_t)(d0 + 1) * 1024] = v.y;
        out_e[obase + (size_t)(d0 + 2) * 1024] = v.z;
        out_e[obase + (size_t)(d0 + 3) * 1024] = v.w;
    }
}

// ---------------------------------------------------------------------------
// FUSED post: recon (bid 0..127) ∥ rescore (bid 128..255) in one launch.
//  - recon skips suspect positions (idx sign bit); rescore writes their recon
//    output itself. Benign races only (both writers produce identical bytes;
//    stale reads see either "flagged" -> skip, or "final" -> same values).
//  - rescore reads the ORIGINAL cb (flag-aware), NOT cbT, because recon's
//    out_r writes clobber the table region that cbT lives in.
// ---------------------------------------------------------------------------
__global__ __launch_bounds__(256) void k_post(
        const float* __restrict__ out_z, const void* __restrict__ cb,
        const double* __restrict__ w2d, int* __restrict__ idx,
        const int* __restrict__ scnt, const int* __restrict__ spos,
        const float* __restrict__ U, const int* __restrict__ flagp,
        float* __restrict__ out_e, float* __restrict__ out_r, int skipTail) {
    __shared__ float zsh[512];
    __shared__ float rs[256];
    __shared__ int rk[256];
    __shared__ int bc[2];
    const int bid = blockIdx.x;
    const int t = threadIdx.x;

    if (bid < 128) {
        // ---- recon role ----
        const int pos = bid * 256 + t;
        const int v0 = idx[pos];
        if (v0 >= 0) {
            const int id = v0 & 511;
            const int b = pos >> 10, sp = pos & 1023, i = sp >> 5, j = sp & 31;
            const float* u = &U[(size_t)id * 48];
            #pragma unroll
            for (int c = 0; c < 3; ++c)
                #pragma unroll
                for (int uu = 0; uu < 4; ++uu) {
                    float4 q = *(const float4*)(&u[c * 16 + uu * 4]);
                    float4 o;
                    o.x = 1.f / (1.f + __expf(-q.x));
                    o.y = 1.f / (1.f + __expf(-q.y));
                    o.z = 1.f / (1.f + __expf(-q.z));
                    o.w = 1.f / (1.f + __expf(-q.w));
                    *(float4*)(&out_r[((size_t)((b * 3 + c) * 128) + (i * 4 + uu)) * 128 + j * 4]) = o;
                }
        }
        return;
    }

    // ---- rescore role ----
    const int flag = *flagp;
    int n = *scnt; if (n > MAXSUS) n = MAXSUS;
    for (int s = bid - 128; s < n; s += 128) {
        int p = spos[s] & 32767;
        int b = p >> 10, sp = p & 1023;
        __syncthreads();
        zsh[t]       = out_z[(size_t)(b * 512 + t) * 1024 + sp];
        zsh[t + 256] = out_z[(size_t)(b * 512 + t + 256) * 1024 + sp];
        __syncthreads();
        float bs = 1e30f; int bk = 511;
        for (int cc = 0; cc < 2; ++cc) {
            int k = t + cc * 256;
            double a = 0.0;
            for (int d = 0; d < 512; ++d)
                a = fma((double)zsh[d], (double)ldin(cb, (size_t)d * 512 + k, flag), a);
            float sc = (float)(w2d[k] - 2.0 * a);
            if (sc < bs || (sc == bs && k < bk)) { bs = sc; bk = k; }
        }
        rs[t] = bs; rk[t] = bk;
        __syncthreads();
        for (int str = 128; str > 0; str >>= 1) {
            if (t < str) {
                float so = rs[t + str]; int ko = rk[t + str];
                if (so < rs[t] || (so == rs[t] && ko < rk[t])) { rs[t] = so; rk[t] = ko; }
            }
            __syncthreads();
        }
        if (t == 0) {
            int kstar = rk[0] & 511;
            int old = idx[p] & 511;
            bc[0] = kstar; bc[1] = (kstar != old);
            idx[p] = kstar;                       // clears suspect flag too
        }
        __syncthreads();
        const int kk = bc[0];
        if (bc[1]) {
            for (int d = t; d < 512; d += 256) {
                if (skipTail && b == 31 && d >= 448) continue;
                out_e[(size_t)(b * 512 + d) * 1024 + sp] = ldin(cb, (size_t)d * 512 + kk, flag);
            }
        }
        // recon for this suspect (recon role skipped it) — always write
        if (t < 48) {
            float q = U[(size_t)kk * 48 + t];
            float o = 1.f / (1.f + __expf(-q));
            int c = t >> 4, uu = (t >> 2) & 3, vv = t & 3;
            int i = sp >> 5, j = sp & 31;
            out_r[((size_t)((b * 3 + c) * 128) + (i * 4 + uu)) * 128 + j * 4 + vv] = o;
        }
    }
}

// ---------------------------------------------------------------------------
__global__ __launch_bounds__(1024) void k_fixup(
        const void* __restrict__ cb, const int* __restrict__ flagp,
        const int* __restrict__ idx, float* __restrict__ out_e) {
    __shared__ int ii[1024];
    __shared__ int sflag;
    const int t = threadIdx.x;
    if (t == 0) sflag = *flagp;
    ii[t] = idx[31744 + t] & 511;
    __syncthreads();
    const int flag = sflag;
    for (int e = t; e < 65536; e += 1024) {
        int d = 448 + (e >> 10), sp = e & 1023;
        out_e[((size_t)(31 * 512 + d)) * 1024 + sp] = ldin(cb, (size_t)d * 512 + ii[sp], flag);
    }
}

// ---------------------------------------------------------------------------
extern "C" void kernel_launch(void* const* d_in, const int* in_sizes, int n_in,
                              void* d_out, int out_size, void* d_ws, size_t ws_size,
                              hipStream_t stream) {
    const void* x  = d_in[0];
    const void* We = d_in[1];
    const void* be = d_in[2];
    const void* Wd = d_in[3];
    const void* bd = d_in[4];
    const void* cb = d_in[5];

    float* out   = (float*)d_out;
    float* out_r = out;                       // 1,572,864 fp32 (6.29 MB)
    float* out_z = out + 1572864;             // 16,777,216 fp32
    float* out_e = out + 18350080;            // 16,777,216 fp32

    // Read-mostly tables in out_r (recon overwrites during k_post; nothing in
    // k_post reads them — rescore uses raw cb):
    char* Rb = (char*)out_r;
    float* cbT          = (float*)(Rb);                    // 1,048,576 B
    float* cWe          = (float*)(Rb + 1048576);          //    98,304 B
    float* cbe          = (float*)(Rb + 1146880);          //     2,048 B
    float* cWd          = (float*)(Rb + 1148928);          //    98,304 B
    float* cbd          = (float*)(Rb + 1247232);          //        64 B
    unsigned short* cbHT= (unsigned short*)(Rb + 1247296); //   524,288 B
    unsigned short* cbLT= (unsigned short*)(Rb + 1771584); //   524,288 B

    // Tail scratch: prefer d_ws; else last 256 KB of out_e (fixup required).
    int tailWS = (ws_size >= 262144) ? 1 : 0;
    char* Tbase = tailWS ? (char*)d_ws : ((char*)out_e + 66846720);
    int skipTail = tailWS ? 0 : 1;
    int*    idx  = (int*)   (Tbase);            // 131,072 B
    float*  U    = (float*) (Tbase + 131072);   //  98,304 B
    float*  w2   = (float*) (Tbase + 229376);   //   2,048 B
    double* w2d  = (double*)(Tbase + 231424);   //   4,096 B
    int*    flag = (int*)   (Tbase + 235520);   //      64 B
    int*    scnt = (int*)   (Tbase + 235584);   //      64 B
    int*    spos = (int*)   (Tbase + 235648);   //  16,384 B

    k_sniff<<<1, 1024, 0, stream>>>(cb, flag, scnt);
    k_prepAll<<<395, 256, 0, stream>>>(We, be, Wd, bd, cb, flag,
                                       cWe, cbe, cWd, cbd,
                                       cbT, cbHT, cbLT, w2, w2d, U);
    k_main<<<512, 256, 0, stream>>>(x, cWe, cbe, flag, cbHT, cbLT, cbT, w2,
                                    out_z, out_e, idx, scnt, spos, skipTail);
    k_post<<<256, 256, 0, stream>>>(out_z, cb, w2d, idx, scnt, spos, U, flag,
                                    out_e, out_r, skipTail);
    if (skipTail)
        k_fixup<<<1, 1024, 0, stream>>>(cb, flag, idx, out_e);
}

// Round 6
// 337.791 us; speedup vs baseline: 1.4340x; 1.0023x over previous
//
#include <hip/hip_runtime.h>
#include <hip/hip_bf16.h>

// B=32, C=3, H=W=128, D=512, K=512, S=4, NPOS=32768
#define NPOS 32768
#define EPS_GAP 4e-3f
#define MAXSUS 4096

typedef __attribute__((ext_vector_type(8))) short short8;
typedef __attribute__((ext_vector_type(4))) float floatx4;

static __device__ __forceinline__ float bfu(unsigned short h) {
    return __uint_as_float(((unsigned int)h) << 16);
}
static __device__ __forceinline__ unsigned short f2bf(float f) {
    unsigned int u = __float_as_uint(f);
    u = (u + 0x7fffu + ((u >> 16) & 1u)) >> 16;   // RNE
    return (unsigned short)u;
}
static __device__ __forceinline__ float ldin(const void* p, size_t i, int flag) {
    return flag ? bfu(((const unsigned short*)p)[i]) : ((const float*)p)[i];
}

// LDS-only barrier: drains ds ops (lgkmcnt) but leaves global loads/stores
// in flight across the barrier (no vmcnt(0) drain).
static __device__ __forceinline__ void ldsbar() {
    asm volatile("s_waitcnt lgkmcnt(0)" ::: "memory");
    __builtin_amdgcn_s_barrier();
    asm volatile("" ::: "memory");
}

// ---------------------------------------------------------------------------
// Sniff: decide bf16 vs fp32 input encoding from codebook column norms.
// ---------------------------------------------------------------------------
__global__ __launch_bounds__(1024) void k_sniff(const void* __restrict__ cb,
                                                int* __restrict__ flag,
                                                int* __restrict__ scnt) {
    __shared__ float s[1024];
    const int t = threadIdx.x;
    const int k = t & 63, g = t >> 6;          // 16 groups x 32 d
    const unsigned short* u = (const unsigned short*)cb;
    float acc = 0.f;
    for (int d = g * 32; d < g * 32 + 32; ++d) {
        float v = bfu(u[(size_t)d * 512 + k]);
        acc = fmaf(v, v, acc);
    }
    s[t] = acc;
    __syncthreads();
    if (t < 64) {
        float a = 0.f;
        #pragma unroll
        for (int g2 = 0; g2 < 16; ++g2) a += s[g2 * 64 + k];
        int ok = (a >= 100.f && a <= 2000.f) ? 1 : 0;
        unsigned long long m = __ballot(ok);
        if (k == 0) {
            *flag = (m == ~0ull) ? 1 : 0;
            *scnt = 0;
        }
    }
}

// ---------------------------------------------------------------------------
// FUSED prep: one launch, role-split by blockIdx. NO cross-role dependencies:
//   bid   0..194 : canonW  (copy We/be/Wd/bd -> canonical fp32)   [reads raw]
//   bid 195..258 : prepcb  (cb -> cbT fp32 [k][d], cbHT/cbLT bf16) [reads raw cb]
//   bid 259..266 : w2      (column norms, fp32+fp64)               [reads raw cb]
//   bid 267..394 : udec    (decoder LUT U[k][48])                  [reads raw cb/Wd/bd]
// udec reads Wd/bd raw (canonW output has no intra-launch ordering).
// ---------------------------------------------------------------------------
__global__ __launch_bounds__(256) void k_prepAll(
        const void* __restrict__ We, const void* __restrict__ be,
        const void* __restrict__ Wd, const void* __restrict__ bd,
        const void* __restrict__ cb, const int* __restrict__ flagp,
        float* __restrict__ cWe, float* __restrict__ cbe,
        float* __restrict__ cWd, float* __restrict__ cbd,
        float* __restrict__ cbT, unsigned short* __restrict__ cbHT,
        unsigned short* __restrict__ cbLT,
        float* __restrict__ w2, double* __restrict__ w2d,
        float* __restrict__ U) {
    __shared__ float tile[64][65];
    __shared__ double sd[256];
    const int bid = blockIdx.x;
    const int t = threadIdx.x;
    const int flag = *flagp;

    if (bid < 195) {
        // ---- canonW ----
        int e = bid * 256 + t;
        if (e < 24576)       cWe[e]         = ldin(We, e, flag);
        else if (e < 25088)  cbe[e - 24576] = ldin(be, e - 24576, flag);
        else if (e < 49664)  cWd[e - 25088] = ldin(Wd, e - 25088, flag);
        else if (e < 49667)  cbd[e - 49664] = ldin(bd, e - 49664, flag);
    } else if (bid < 259) {
        // ---- prepcb ----
        const int bb = bid - 195;
        const int D0 = (bb >> 3) * 64, K0 = (bb & 7) * 64;
        for (int it = 0; it < 16; ++it) {
            int r = (t >> 6) + 4 * it, c = t & 63;
            tile[r][c] = ldin(cb, (size_t)(D0 + r) * 512 + K0 + c, flag);
        }
        __syncthreads();
        for (int it = 0; it < 16; ++it) {
            int r = (t >> 6) + 4 * it, c = t & 63;
            float v = tile[c][r];
            size_t o = (size_t)(K0 + r) * 512 + D0 + c;
            cbT[o] = v;
            unsigned short h = f2bf(v);
            cbHT[o] = h;
            cbLT[o] = f2bf(v - bfu(h));
        }
    } else if (bid < 267) {
        // ---- w2 ----
        const int k = (bid - 259) * 64 + (t & 63);
        const int g = t >> 6;                  // 4 groups x 128 d
        double acc = 0.0;
        for (int d = g * 128; d < g * 128 + 128; ++d) {
            double v = (double)ldin(cb, (size_t)d * 512 + k, flag);
            acc += v * v;
        }
        sd[t] = acc;
        __syncthreads();
        if (t < 64) {
            double a = sd[t] + sd[t + 64] + sd[t + 128] + sd[t + 192];
            w2[k] = (float)a;
            w2d[k] = a;
        }
    } else {
        // ---- udec: U[k][c*16+u*4+v] = sum_d cb[d][k]*Wd[c][d][3-u][3-v]+bd[c]
        const int kk = (bid - 267) * 4 + (t >> 6);
        const int lane = t & 63;
        const int j = lane >> 2, dpart = lane & 3;
        const int u = (j >> 2) & 3, v = j & 3;
        int woff[3];
        #pragma unroll
        for (int m = 0; m < 3; ++m) woff[m] = m * 8192 + (3 - u) * 4 + (3 - v);
        float a0 = 0.f, a1 = 0.f, a2 = 0.f;
        for (int i = 0; i < 128; ++i) {
            int d = dpart * 128 + i;
            float cw = ldin(cb, (size_t)d * 512 + kk, flag);
            a0 = fmaf(cw, ldin(Wd, (size_t)(woff[0] + d * 16), flag), a0);
            a1 = fmaf(cw, ldin(Wd, (size_t)(woff[1] + d * 16), flag), a1);
            a2 = fmaf(cw, ldin(Wd, (size_t)(woff[2] + d * 16), flag), a2);
        }
        a0 += __shfl_xor(a0, 1); a0 += __shfl_xor(a0, 2);
        a1 += __shfl_xor(a1, 1); a1 += __shfl_xor(a1, 2);
        a2 += __shfl_xor(a2, 1); a2 += __shfl_xor(a2, 2);
        if (dpart == 0) {
            U[kk * 48 +  0 + j] = a0 + ldin(bd, 0, flag);
            U[kk * 48 + 16 + j] = a1 + ldin(bd, 1, flag);
            U[kk * 48 + 32 + j] = a2 + ldin(bd, 2, flag);
        }
    }
}

// ---------------------------------------------------------------------------
// k_main helpers (zq = pair base: zH = zq, zL = zq + 2560 shorts; rows 40 shorts)
// conv_step writes out_z directly from registers.
// ---------------------------------------------------------------------------
static __device__ __forceinline__ void conv_step(
        const float* __restrict__ patch, const float* __restrict__ cWe,
        const float* __restrict__ cbe, int dc, int t,
        unsigned short* __restrict__ zq,
        float* __restrict__ out_z, int b, int SP0) {
    const int cd = t & 31;
    const int ps = (t >> 5) * 8;
    const float4* wv = (const float4*)(cWe + (size_t)(dc + cd) * 48);
    const float bias = cbe[dc + cd];
    float za[8];
    #pragma unroll
    for (int p = 0; p < 8; ++p) za[p] = bias;
    #pragma unroll
    for (int q4 = 0; q4 < 12; ++q4) {
        float4 wq = wv[q4];
        #pragma unroll
        for (int p = 0; p < 8; ++p) {
            float4 v = ((const float4*)(patch + (ps + p) * 48))[q4];
            za[p] = fmaf(v.x, wq.x, za[p]);
            za[p] = fmaf(v.y, wq.y, za[p]);
            za[p] = fmaf(v.z, wq.z, za[p]);
            za[p] = fmaf(v.w, wq.w, za[p]);
        }
    }
    float zf[8];
    #pragma unroll
    for (int p = 0; p < 8; ++p) {
        float z = fmaxf(za[p], 0.f);
        unsigned short h = f2bf(z);
        unsigned short l = f2bf(z - bfu(h));
        zq[(ps + p) * 40 + cd] = h;
        zq[2560 + (ps + p) * 40 + cd] = l;
        zf[p] = bfu(h) + bfu(l);
    }
    size_t zbase = (size_t)(b * 512 + dc + cd) * 1024 + SP0 + ps;
    *(float4*)(out_z + zbase)     = (float4){zf[0], zf[1], zf[2], zf[3]};
    *(float4*)(out_z + zbase + 4) = (float4){zf[4], zf[5], zf[6], zf[7]};
}

static __device__ __forceinline__ void mfma_step(
        const unsigned short* __restrict__ zq,
        const unsigned short* __restrict__ cbHT,
        const unsigned short* __restrict__ cbLT,
        int dcPrev, int wave, int quad, int lcol, int flag, floatx4 (&acc)[4][8]) {
    short8 aH[4], aL[4];
    #pragma unroll
    for (int mt = 0; mt < 4; ++mt) {
        aH[mt] = *(const short8*)(zq + (mt * 16 + lcol) * 40 + quad * 8);
        aL[mt] = *(const short8*)(zq + 2560 + (mt * 16 + lcol) * 40 + quad * 8);
    }
    #pragma unroll
    for (int j = 0; j < 8; ++j) {
        int code = (wave * 8 + j) * 16 + lcol;
        short8 bH = *(const short8*)(cbHT + (size_t)code * 512 + dcPrev + quad * 8);
        #pragma unroll
        for (int mt = 0; mt < 4; ++mt) {
            acc[mt][j] = __builtin_amdgcn_mfma_f32_16x16x32_bf16(aH[mt], bH, acc[mt][j], 0, 0, 0);
            acc[mt][j] = __builtin_amdgcn_mfma_f32_16x16x32_bf16(aL[mt], bH, acc[mt][j], 0, 0, 0);
        }
    }
    if (!flag) {   // fp32 inputs: third term zh*cbL
        #pragma unroll
        for (int j = 0; j < 8; ++j) {
            int code = (wave * 8 + j) * 16 + lcol;
            short8 bL = *(const short8*)(cbLT + (size_t)code * 512 + dcPrev + quad * 8);
            #pragma unroll
            for (int mt = 0; mt < 4; ++mt)
                acc[mt][j] = __builtin_amdgcn_mfma_f32_16x16x32_bf16(aH[mt], bL, acc[mt][j], 0, 0, 0);
        }
    }
}

// best/second combine: (a1,ak,a2) <- merge (o1,ok,o2)
static __device__ __forceinline__ void bmerge(float& a1, int& ak, float& a2,
                                              float o1, int ok, float o2) {
    if (o1 < a1)      { a2 = fminf(a1, o2); a1 = o1; ak = ok; }
    else if (o1 > a1) { a2 = fminf(a2, o1); }
    else              { a2 = a1; if (ok < ak) ak = ok; }   // exact tie -> gap 0 (suspect)
}

// ---------------------------------------------------------------------------
// FUSED main v8 = v7 + XCD-aware block swizzle: q = (bid%8)*64 + bid/8
// (bijective for grid 512). Hardware round-robins bid%8 -> XCD, so XCD x
// receives contiguous tiles q in [64x, 64x+64) = batches 4x..4x+3. All blocks
// on one XCD then share the same out_z/out_e 4KB rows -> their 256B write
// fragments merge in that XCD's L2 into near-full rows before HBM eviction.
// (Theory: k_main is write-pattern-bound; 256B @4KB-stride scatter across 8
// non-coherent L2s is the 783 GB/s ceiling seen in r0-r5.)
// ---------------------------------------------------------------------------
__global__ __launch_bounds__(256, 2) void k_main(
        const void* __restrict__ x, const float* __restrict__ cWe,
        const float* __restrict__ cbe, const int* __restrict__ flagp,
        const unsigned short* __restrict__ cbHT, const unsigned short* __restrict__ cbLT,
        const float* __restrict__ cbT, const float* __restrict__ w2,
        float* __restrict__ out_z, float* __restrict__ out_e,
        int* __restrict__ idx, int* __restrict__ scnt, int* __restrict__ spos,
        int skipTail) {
    __shared__ __align__(16) char smc[32768];
    float* patch = (float*)smc;                               // [64][48] fp32
    unsigned short* zb = (unsigned short*)(smc + 12288);      // 2 pairs x 5120 shorts

    const int t = threadIdx.x;
    const int bid = blockIdx.x;
    const int q = ((bid & 7) << 6) | (bid >> 3);   // XCD co-location swizzle
    const int P0 = q * 64;
    const int b = P0 >> 10, SP0 = P0 & 1023;
    const int flag = *flagp;
    const int wave = t >> 6, lane = t & 63;
    const int quad = lane >> 4, lcol = lane & 15;

    // stage x patches once
    for (int e = t; e < 3072; e += 256) {
        int pid = e / 48, kk = e % 48;
        int c = kk >> 4, r = (kk >> 2) & 3, s = kk & 3;
        int pos = P0 + pid;
        int bb = pos >> 10, sp = pos & 1023, i = sp >> 5, j = sp & 31;
        patch[pid * 48 + kk] = ldin(x, ((bb * 3 + c) * 128 + (i * 4 + r)) * 128 + (j * 4 + s), flag);
    }

    floatx4 acc[4][8];
    #pragma unroll
    for (int mt = 0; mt < 4; ++mt)
        #pragma unroll
        for (int j = 0; j < 8; ++j) acc[mt][j] = (floatx4){0.f, 0.f, 0.f, 0.f};

    ldsbar();
    conv_step(patch, cWe, cbe, 0, t, zb, out_z, b, SP0);      // chunk 0 -> pair 0
    for (int dc = 32; dc < 512; dc += 32) {
        ldsbar();
        const int p = (dc >> 5) & 1;
        conv_step(patch, cWe, cbe, dc, t, zb + p * 5120, out_z, b, SP0);
        mfma_step(zb + (p ^ 1) * 5120, cbHT, cbLT, dc - 32, wave, quad, lcol, flag, acc);
    }
    ldsbar();
    mfma_step(zb + 5120, cbHT, cbLT, 480, wave, quad, lcol, flag, acc);

    // ---- epilogue: per-lane best/second over its 8 codes, then shuffle ----
    float s1[4][4], s2[4][4]; int k1[4][4];
    #pragma unroll
    for (int mt = 0; mt < 4; ++mt)
        #pragma unroll
        for (int r = 0; r < 4; ++r) { s1[mt][r] = 1e30f; s2[mt][r] = 1e30f; k1[mt][r] = 511; }
    #pragma unroll
    for (int j = 0; j < 8; ++j) {
        int code = (wave * 8 + j) * 16 + lcol;
        float wk = w2[code];
        #pragma unroll
        for (int mt = 0; mt < 4; ++mt)
            #pragma unroll
            for (int r = 0; r < 4; ++r) {
                float s = wk - 2.f * acc[mt][j][r];
                bmerge(s1[mt][r], k1[mt][r], s2[mt][r], s, code, 1e30f);
            }
    }
    // overlay reduction arrays on patch region (patch dead after last conv+bar)
    float* sS1 = (float*)smc;             // [64 pos][4 wave]
    int*   sK1 = (int*)(smc + 1024);
    float* sS2 = (float*)(smc + 2048);
    int*   ii  = (int*)(smc + 3072);      // [64]
    #pragma unroll
    for (int mt = 0; mt < 4; ++mt)
        #pragma unroll
        for (int r = 0; r < 4; ++r) {
            float a1 = s1[mt][r], a2 = s2[mt][r]; int ak = k1[mt][r];
            #pragma unroll
            for (int m = 1; m < 16; m <<= 1) {
                float o1 = __shfl_xor(a1, m);
                float o2 = __shfl_xor(a2, m);
                int   ok = __shfl_xor(ak, m);
                bmerge(a1, ak, a2, o1, ok, o2);
            }
            if (lcol == 0) {
                int pos = mt * 16 + quad * 4 + r;
                sS1[pos * 4 + wave] = a1;
                sK1[pos * 4 + wave] = ak;
                sS2[pos * 4 + wave] = a2;
            }
        }
    __syncthreads();
    if (t < 64) {
        float a1 = sS1[t * 4]; int ak = sK1[t * 4]; float a2 = sS2[t * 4];
        #pragma unroll
        for (int w = 1; w < 4; ++w)
            bmerge(a1, ak, a2, sS1[t * 4 + w], sK1[t * 4 + w], sS2[t * 4 + w]);
        ak &= 511;
        ii[t] = ak;
        unsigned int flagged = 0u;
        if (a2 - a1 < EPS_GAP) {
            int slot = atomicAdd(scnt, 1);
            if (slot < MAXSUS) { spos[slot] = P0 + t; flagged = 1u; }
        }
        idx[P0 + t] = (int)((unsigned)ak | (flagged << 31));
    }
    __syncthreads();

    // ---- fused emb: out_e[b][d][SP0+sp] = cbT[ii[sp]][d] ----
    const int sp = t & 63, dq = t >> 6;
    const float* row = cbT + (size_t)ii[sp] * 512;
    const size_t obase = ((size_t)b * 512) * 1024 + SP0 + sp;
    for (int d0 = dq * 128; d0 < dq * 128 + 128; d0 += 4) {
        if (skipTail && b == 31 && d0 >= 448) break;
        float4 v = *(const float4*)(row + d0);
        out_e[obase + (size_t)(d0    ) * 1024] = v.x;
        out_e[obase + (size_t)(d0 + 1) * 1024] = v.y;
        out_e[obase + (size_t)(d0 + 2) * 1024] = v.z;
        out_e[obase + (size_t)(d0 + 3) * 1024] = v.w;
    }
}

// ---------------------------------------------------------------------------
// FUSED post: recon (bid 0..127) ∥ rescore (bid 128..255) in one launch.
// ---------------------------------------------------------------------------
__global__ __launch_bounds__(256) void k_post(
        const float* __restrict__ out_z, const void* __restrict__ cb,
        const double* __restrict__ w2d, int* __restrict__ idx,
        const int* __restrict__ scnt, const int* __restrict__ spos,
        const float* __restrict__ U, const int* __restrict__ flagp,
        float* __restrict__ out_e, float* __restrict__ out_r, int skipTail) {
    __shared__ float zsh[512];
    __shared__ float rs[256];
    __shared__ int rk[256];
    __shared__ int bc[2];
    const int bid = blockIdx.x;
    const int t = threadIdx.x;

    if (bid < 128) {
        // ---- recon role ----
        const int pos = bid * 256 + t;
        const int v0 = idx[pos];
        if (v0 >= 0) {
            const int id = v0 & 511;
            const int b = pos >> 10, sp = pos & 1023, i = sp >> 5, j = sp & 31;
            const float* u = &U[(size_t)id * 48];
            #pragma unroll
            for (int c = 0; c < 3; ++c)
                #pragma unroll
                for (int uu = 0; uu < 4; ++uu) {
                    float4 q = *(const float4*)(&u[c * 16 + uu * 4]);
                    float4 o;
                    o.x = 1.f / (1.f + __expf(-q.x));
                    o.y = 1.f / (1.f + __expf(-q.y));
                    o.z = 1.f / (1.f + __expf(-q.z));
                    o.w = 1.f / (1.f + __expf(-q.w));
                    *(float4*)(&out_r[((size_t)((b * 3 + c) * 128) + (i * 4 + uu)) * 128 + j * 4]) = o;
                }
        }
        return;
    }

    // ---- rescore role ----
    const int flag = *flagp;
    int n = *scnt; if (n > MAXSUS) n = MAXSUS;
    for (int s = bid - 128; s < n; s += 128) {
        int p = spos[s] & 32767;
        int b = p >> 10, sp = p & 1023;
        __syncthreads();
        zsh[t]       = out_z[(size_t)(b * 512 + t) * 1024 + sp];
        zsh[t + 256] = out_z[(size_t)(b * 512 + t + 256) * 1024 + sp];
        __syncthreads();
        float bs = 1e30f; int bk = 511;
        for (int cc = 0; cc < 2; ++cc) {
            int k = t + cc * 256;
            double a = 0.0;
            for (int d = 0; d < 512; ++d)
                a = fma((double)zsh[d], (double)ldin(cb, (size_t)d * 512 + k, flag), a);
            float sc = (float)(w2d[k] - 2.0 * a);
            if (sc < bs || (sc == bs && k < bk)) { bs = sc; bk = k; }
        }
        rs[t] = bs; rk[t] = bk;
        __syncthreads();
        for (int str = 128; str > 0; str >>= 1) {
            if (t < str) {
                float so = rs[t + str]; int ko = rk[t + str];
                if (so < rs[t] || (so == rs[t] && ko < rk[t])) { rs[t] = so; rk[t] = ko; }
            }
            __syncthreads();
        }
        if (t == 0) {
            int kstar = rk[0] & 511;
            int old = idx[p] & 511;
            bc[0] = kstar; bc[1] = (kstar != old);
            idx[p] = kstar;                       // clears suspect flag too
        }
        __syncthreads();
        const int kk = bc[0];
        if (bc[1]) {
            for (int d = t; d < 512; d += 256) {
                if (skipTail && b == 31 && d >= 448) continue;
                out_e[(size_t)(b * 512 + d) * 1024 + sp] = ldin(cb, (size_t)d * 512 + kk, flag);
            }
        }
        // recon for this suspect (recon role skipped it) — always write
        if (t < 48) {
            float q = U[(size_t)kk * 48 + t];
            float o = 1.f / (1.f + __expf(-q));
            int c = t >> 4, uu = (t >> 2) & 3, vv = t & 3;
            int i = sp >> 5, j = sp & 31;
            out_r[((size_t)((b * 3 + c) * 128) + (i * 4 + uu)) * 128 + j * 4 + vv] = o;
        }
    }
}

// ---------------------------------------------------------------------------
__global__ __launch_bounds__(1024) void k_fixup(
        const void* __restrict__ cb, const int* __restrict__ flagp,
        const int* __restrict__ idx, float* __restrict__ out_e) {
    __shared__ int ii[1024];
    __shared__ int sflag;
    const int t = threadIdx.x;
    if (t == 0) sflag = *flagp;
    ii[t] = idx[31744 + t] & 511;
    __syncthreads();
    const int flag = sflag;
    for (int e = t; e < 65536; e += 1024) {
        int d = 448 + (e >> 10), sp = e & 1023;
        out_e[((size_t)(31 * 512 + d)) * 1024 + sp] = ldin(cb, (size_t)d * 512 + ii[sp], flag);
    }
}

// ---------------------------------------------------------------------------
extern "C" void kernel_launch(void* const* d_in, const int* in_sizes, int n_in,
                              void* d_out, int out_size, void* d_ws, size_t ws_size,
                              hipStream_t stream) {
    const void* x  = d_in[0];
    const void* We = d_in[1];
    const void* be = d_in[2];
    const void* Wd = d_in[3];
    const void* bd = d_in[4];
    const void* cb = d_in[5];

    float* out   = (float*)d_out;
    float* out_r = out;                       // 1,572,864 fp32 (6.29 MB)
    float* out_z = out + 1572864;             // 16,777,216 fp32
    float* out_e = out + 18350080;            // 16,777,216 fp32

    // Read-mostly tables in out_r (recon overwrites during k_post; nothing in
    // k_post reads them — rescore uses raw cb):
    char* Rb = (char*)out_r;
    float* cbT          = (float*)(Rb);                    // 1,048,576 B
    float* cWe          = (float*)(Rb + 1048576);          //    98,304 B
    float* cbe          = (float*)(Rb + 1146880);          //     2,048 B
    float* cWd          = (float*)(Rb + 1148928);          //    98,304 B
    float* cbd          = (float*)(Rb + 1247232);          //        64 B
    unsigned short* cbHT= (unsigned short*)(Rb + 1247296); //   524,288 B
    unsigned short* cbLT= (unsigned short*)(Rb + 1771584); //   524,288 B

    // Tail scratch: prefer d_ws; else last 256 KB of out_e (fixup required).
    int tailWS = (ws_size >= 262144) ? 1 : 0;
    char* Tbase = tailWS ? (char*)d_ws : ((char*)out_e + 66846720);
    int skipTail = tailWS ? 0 : 1;
    int*    idx  = (int*)   (Tbase);            // 131,072 B
    float*  U    = (float*) (Tbase + 131072);   //  98,304 B
    float*  w2   = (float*) (Tbase + 229376);   //   2,048 B
    double* w2d  = (double*)(Tbase + 231424);   //   4,096 B
    int*    flag = (int*)   (Tbase + 235520);   //      64 B
    int*    scnt = (int*)   (Tbase + 235584);   //      64 B
    int*    spos = (int*)   (Tbase + 235648);   //  16,384 B

    k_sniff<<<1, 1024, 0, stream>>>(cb, flag, scnt);
    k_prepAll<<<395, 256, 0, stream>>>(We, be, Wd, bd, cb, flag,
                                       cWe, cbe, cWd, cbd,
                                       cbT, cbHT, cbLT, w2, w2d, U);
    k_main<<<512, 256, 0, stream>>>(x, cWe, cbe, flag, cbHT, cbLT, cbT, w2,
                                    out_z, out_e, idx, scnt, spos, skipTail);
    k_post<<<256, 256, 0, stream>>>(out_z, cb, w2d, idx, scnt, spos, U, flag,
                                    out_e, out_r, skipTail);
    if (skipTail)
        k_fixup<<<1, 1024, 0, stream>>>(cb, flag, idx, out_e);
}

// Round 7
// 274.809 us; speedup vs baseline: 1.7627x; 1.2292x over previous
//
#include <hip/hip_runtime.h>
#include <hip/hip_bf16.h>

// B=32, C=3, H=W=128, D=512, K=512, S=4, NPOS=32768
#define NPOS 32768
#define EPS_GAP 4e-3f
#define MAXSUS 4096

typedef __attribute__((ext_vector_type(8))) short short8;
typedef __attribute__((ext_vector_type(4))) float floatx4;

static __device__ __forceinline__ float bfu(unsigned short h) {
    return __uint_as_float(((unsigned int)h) << 16);
}
static __device__ __forceinline__ unsigned short f2bf(float f) {
    unsigned int u = __float_as_uint(f);
    u = (u + 0x7fffu + ((u >> 16) & 1u)) >> 16;   // RNE
    return (unsigned short)u;
}
static __device__ __forceinline__ float ldin(const void* p, size_t i, int flag) {
    return flag ? bfu(((const unsigned short*)p)[i]) : ((const float*)p)[i];
}

// LDS-only barrier: drains ds ops (lgkmcnt) but leaves global loads/stores
// in flight across the barrier (no vmcnt(0) drain).
static __device__ __forceinline__ void ldsbar() {
    asm volatile("s_waitcnt lgkmcnt(0)" ::: "memory");
    __builtin_amdgcn_s_barrier();
    asm volatile("" ::: "memory");
}

// Swizzled B-fragment offset (units: shorts). Element (code k, dim d) lands at
// the position the MFMA lane-load wants: fragment(chunk=d>>5, codeTile=k>>4)
// is 64 lanes x 8 shorts contiguous; lane = ((d>>3)&3)*16 + (k&15), sub = d&7.
// mfma load address: dc*512 + (wave*8+j)*512 + lane*8  -> lane*16B coalesced.
static __device__ __forceinline__ size_t swzoff(int k, int d) {
    return (size_t)(d >> 5) * 16384 + (size_t)(k >> 4) * 512
         + (size_t)((((d >> 3) & 3) * 16 + (k & 15)) * 8) + (d & 7);
}

// ---------------------------------------------------------------------------
// Sniff: decide bf16 vs fp32 input encoding from codebook column norms.
// ---------------------------------------------------------------------------
__global__ __launch_bounds__(1024) void k_sniff(const void* __restrict__ cb,
                                                int* __restrict__ flag,
                                                int* __restrict__ scnt) {
    __shared__ float s[1024];
    const int t = threadIdx.x;
    const int k = t & 63, g = t >> 6;          // 16 groups x 32 d
    const unsigned short* u = (const unsigned short*)cb;
    float acc = 0.f;
    for (int d = g * 32; d < g * 32 + 32; ++d) {
        float v = bfu(u[(size_t)d * 512 + k]);
        acc = fmaf(v, v, acc);
    }
    s[t] = acc;
    __syncthreads();
    if (t < 64) {
        float a = 0.f;
        #pragma unroll
        for (int g2 = 0; g2 < 16; ++g2) a += s[g2 * 64 + k];
        int ok = (a >= 100.f && a <= 2000.f) ? 1 : 0;
        unsigned long long m = __ballot(ok);
        if (k == 0) {
            *flag = (m == ~0ull) ? 1 : 0;
            *scnt = 0;
        }
    }
}

// ---------------------------------------------------------------------------
// FUSED prep: one launch, role-split by blockIdx. NO cross-role dependencies:
//   bid   0..194 : canonW  (copy We/be/Wd/bd -> canonical fp32)   [reads raw]
//   bid 195..258 : prepcb  (cb -> cbT fp32 [k][d]; cbHS/cbLS bf16-split in
//                           SWIZZLED fragment order)               [reads raw cb]
//   bid 259..266 : w2      (column norms, fp32+fp64)               [reads raw cb]
//   bid 267..394 : udec    (decoder LUT U[k][48])                  [reads raw cb/Wd/bd]
// ---------------------------------------------------------------------------
__global__ __launch_bounds__(256) void k_prepAll(
        const void* __restrict__ We, const void* __restrict__ be,
        const void* __restrict__ Wd, const void* __restrict__ bd,
        const void* __restrict__ cb, const int* __restrict__ flagp,
        float* __restrict__ cWe, float* __restrict__ cbe,
        float* __restrict__ cWd, float* __restrict__ cbd,
        float* __restrict__ cbT, unsigned short* __restrict__ cbHS,
        unsigned short* __restrict__ cbLS,
        float* __restrict__ w2, double* __restrict__ w2d,
        float* __restrict__ U) {
    __shared__ float tile[64][65];
    __shared__ double sd[256];
    const int bid = blockIdx.x;
    const int t = threadIdx.x;
    const int flag = *flagp;

    if (bid < 195) {
        // ---- canonW ----
        int e = bid * 256 + t;
        if (e < 24576)       cWe[e]         = ldin(We, e, flag);
        else if (e < 25088)  cbe[e - 24576] = ldin(be, e - 24576, flag);
        else if (e < 49664)  cWd[e - 25088] = ldin(Wd, e - 25088, flag);
        else if (e < 49667)  cbd[e - 49664] = ldin(bd, e - 49664, flag);
    } else if (bid < 259) {
        // ---- prepcb ----
        const int bb = bid - 195;
        const int D0 = (bb >> 3) * 64, K0 = (bb & 7) * 64;
        for (int it = 0; it < 16; ++it) {
            int r = (t >> 6) + 4 * it, c = t & 63;
            tile[r][c] = ldin(cb, (size_t)(D0 + r) * 512 + K0 + c, flag);
        }
        __syncthreads();
        for (int it = 0; it < 16; ++it) {
            int r = (t >> 6) + 4 * it, c = t & 63;
            float v = tile[c][r];
            int k = K0 + r, d = D0 + c;
            cbT[(size_t)k * 512 + d] = v;
            size_t o2 = swzoff(k, d);
            unsigned short h = f2bf(v);
            cbHS[o2] = h;
            cbLS[o2] = f2bf(v - bfu(h));
        }
    } else if (bid < 267) {
        // ---- w2 ----
        const int k = (bid - 259) * 64 + (t & 63);
        const int g = t >> 6;                  // 4 groups x 128 d
        double acc = 0.0;
        for (int d = g * 128; d < g * 128 + 128; ++d) {
            double v = (double)ldin(cb, (size_t)d * 512 + k, flag);
            acc += v * v;
        }
        sd[t] = acc;
        __syncthreads();
        if (t < 64) {
            double a = sd[t] + sd[t + 64] + sd[t + 128] + sd[t + 192];
            w2[k] = (float)a;
            w2d[k] = a;
        }
    } else {
        // ---- udec: U[k][c*16+u*4+v] = sum_d cb[d][k]*Wd[c][d][3-u][3-v]+bd[c]
        const int kk = (bid - 267) * 4 + (t >> 6);
        const int lane = t & 63;
        const int j = lane >> 2, dpart = lane & 3;
        const int u = (j >> 2) & 3, v = j & 3;
        int woff[3];
        #pragma unroll
        for (int m = 0; m < 3; ++m) woff[m] = m * 8192 + (3 - u) * 4 + (3 - v);
        float a0 = 0.f, a1 = 0.f, a2 = 0.f;
        for (int i = 0; i < 128; ++i) {
            int d = dpart * 128 + i;
            float cw = ldin(cb, (size_t)d * 512 + kk, flag);
            a0 = fmaf(cw, ldin(Wd, (size_t)(woff[0] + d * 16), flag), a0);
            a1 = fmaf(cw, ldin(Wd, (size_t)(woff[1] + d * 16), flag), a1);
            a2 = fmaf(cw, ldin(Wd, (size_t)(woff[2] + d * 16), flag), a2);
        }
        a0 += __shfl_xor(a0, 1); a0 += __shfl_xor(a0, 2);
        a1 += __shfl_xor(a1, 1); a1 += __shfl_xor(a1, 2);
        a2 += __shfl_xor(a2, 1); a2 += __shfl_xor(a2, 2);
        if (dpart == 0) {
            U[kk * 48 +  0 + j] = a0 + ldin(bd, 0, flag);
            U[kk * 48 + 16 + j] = a1 + ldin(bd, 1, flag);
            U[kk * 48 + 32 + j] = a2 + ldin(bd, 2, flag);
        }
    }
}

// ---------------------------------------------------------------------------
// k_main helpers (zq = pair base: zH = zq, zL = zq + 2560 shorts; rows 40 shorts)
// conv_step writes out_z directly from registers.
// ---------------------------------------------------------------------------
static __device__ __forceinline__ void conv_step(
        const float* __restrict__ patch, const float* __restrict__ cWe,
        const float* __restrict__ cbe, int dc, int t,
        unsigned short* __restrict__ zq,
        float* __restrict__ out_z, int b, int SP0) {
    const int cd = t & 31;
    const int ps = (t >> 5) * 8;
    const float4* wv = (const float4*)(cWe + (size_t)(dc + cd) * 48);
    const float bias = cbe[dc + cd];
    float za[8];
    #pragma unroll
    for (int p = 0; p < 8; ++p) za[p] = bias;
    #pragma unroll
    for (int q4 = 0; q4 < 12; ++q4) {
        float4 wq = wv[q4];
        #pragma unroll
        for (int p = 0; p < 8; ++p) {
            float4 v = ((const float4*)(patch + (ps + p) * 48))[q4];
            za[p] = fmaf(v.x, wq.x, za[p]);
            za[p] = fmaf(v.y, wq.y, za[p]);
            za[p] = fmaf(v.z, wq.z, za[p]);
            za[p] = fmaf(v.w, wq.w, za[p]);
        }
    }
    float zf[8];
    #pragma unroll
    for (int p = 0; p < 8; ++p) {
        float z = fmaxf(za[p], 0.f);
        unsigned short h = f2bf(z);
        unsigned short l = f2bf(z - bfu(h));
        zq[(ps + p) * 40 + cd] = h;
        zq[2560 + (ps + p) * 40 + cd] = l;
        zf[p] = bfu(h) + bfu(l);
    }
    size_t zbase = (size_t)(b * 512 + dc + cd) * 1024 + SP0 + ps;
    *(float4*)(out_z + zbase)     = (float4){zf[0], zf[1], zf[2], zf[3]};
    *(float4*)(out_z + zbase + 4) = (float4){zf[4], zf[5], zf[6], zf[7]};
}

// B loads now read the swizzled fragment layout: for code-tile (wave*8+j) at
// chunk dcPrev, lane L reads 16B at cbHS + dcPrev*512 + (wave*8+j)*512 + L*8
// -> one fully-coalesced 1KB wave-load (was: 64 lines 1KB apart, 1/4-used).
static __device__ __forceinline__ void mfma_step(
        const unsigned short* __restrict__ zq,
        const unsigned short* __restrict__ cbHS,
        const unsigned short* __restrict__ cbLS,
        int dcPrev, int wave, int quad, int lcol, int flag, floatx4 (&acc)[4][8]) {
    const int lane = quad * 16 + lcol;
    short8 aH[4], aL[4];
    #pragma unroll
    for (int mt = 0; mt < 4; ++mt) {
        aH[mt] = *(const short8*)(zq + (mt * 16 + lcol) * 40 + quad * 8);
        aL[mt] = *(const short8*)(zq + 2560 + (mt * 16 + lcol) * 40 + quad * 8);
    }
    const unsigned short* fbH = cbHS + (size_t)dcPrev * 512 + (size_t)(wave * 8) * 512 + lane * 8;
    #pragma unroll
    for (int j = 0; j < 8; ++j) {
        short8 bH = *(const short8*)(fbH + j * 512);
        #pragma unroll
        for (int mt = 0; mt < 4; ++mt) {
            acc[mt][j] = __builtin_amdgcn_mfma_f32_16x16x32_bf16(aH[mt], bH, acc[mt][j], 0, 0, 0);
            acc[mt][j] = __builtin_amdgcn_mfma_f32_16x16x32_bf16(aL[mt], bH, acc[mt][j], 0, 0, 0);
        }
    }
    if (!flag) {   // fp32 inputs: third term zh*cbL
        const unsigned short* fbL = cbLS + (size_t)dcPrev * 512 + (size_t)(wave * 8) * 512 + lane * 8;
        #pragma unroll
        for (int j = 0; j < 8; ++j) {
            short8 bL = *(const short8*)(fbL + j * 512);
            #pragma unroll
            for (int mt = 0; mt < 4; ++mt)
                acc[mt][j] = __builtin_amdgcn_mfma_f32_16x16x32_bf16(aH[mt], bL, acc[mt][j], 0, 0, 0);
        }
    }
}

// best/second combine: (a1,ak,a2) <- merge (o1,ok,o2)
static __device__ __forceinline__ void bmerge(float& a1, int& ak, float& a2,
                                              float o1, int ok, float o2) {
    if (o1 < a1)      { a2 = fminf(a1, o2); a1 = o1; ak = ok; }
    else if (o1 > a1) { a2 = fminf(a2, o1); }
    else              { a2 = a1; if (ok < ak) ak = ok; }   // exact tie -> gap 0 (suspect)
}

// ---------------------------------------------------------------------------
// FUSED main v9 = v8 + swizzled (coalesced) B-fragment loads. All values and
// accumulation order bit-identical to v8; only the memory layout of the bf16
// codebook tables changed.
// ---------------------------------------------------------------------------
__global__ __launch_bounds__(256, 2) void k_main(
        const void* __restrict__ x, const float* __restrict__ cWe,
        const float* __restrict__ cbe, const int* __restrict__ flagp,
        const unsigned short* __restrict__ cbHS, const unsigned short* __restrict__ cbLS,
        const float* __restrict__ cbT, const float* __restrict__ w2,
        float* __restrict__ out_z, float* __restrict__ out_e,
        int* __restrict__ idx, int* __restrict__ scnt, int* __restrict__ spos,
        int skipTail) {
    __shared__ __align__(16) char smc[32768];
    float* patch = (float*)smc;                               // [64][48] fp32
    unsigned short* zb = (unsigned short*)(smc + 12288);      // 2 pairs x 5120 shorts

    const int t = threadIdx.x;
    const int bid = blockIdx.x;
    const int q = ((bid & 7) << 6) | (bid >> 3);   // XCD co-location swizzle
    const int P0 = q * 64;
    const int b = P0 >> 10, SP0 = P0 & 1023;
    const int flag = *flagp;
    const int wave = t >> 6, lane = t & 63;
    const int quad = lane >> 4, lcol = lane & 15;

    // stage x patches once
    for (int e = t; e < 3072; e += 256) {
        int pid = e / 48, kk = e % 48;
        int c = kk >> 4, r = (kk >> 2) & 3, s = kk & 3;
        int pos = P0 + pid;
        int bb = pos >> 10, sp = pos & 1023, i = sp >> 5, j = sp & 31;
        patch[pid * 48 + kk] = ldin(x, ((bb * 3 + c) * 128 + (i * 4 + r)) * 128 + (j * 4 + s), flag);
    }

    floatx4 acc[4][8];
    #pragma unroll
    for (int mt = 0; mt < 4; ++mt)
        #pragma unroll
        for (int j = 0; j < 8; ++j) acc[mt][j] = (floatx4){0.f, 0.f, 0.f, 0.f};

    ldsbar();
    conv_step(patch, cWe, cbe, 0, t, zb, out_z, b, SP0);      // chunk 0 -> pair 0
    for (int dc = 32; dc < 512; dc += 32) {
        ldsbar();
        const int p = (dc >> 5) & 1;
        conv_step(patch, cWe, cbe, dc, t, zb + p * 5120, out_z, b, SP0);
        mfma_step(zb + (p ^ 1) * 5120, cbHS, cbLS, dc - 32, wave, quad, lcol, flag, acc);
    }
    ldsbar();
    mfma_step(zb + 5120, cbHS, cbLS, 480, wave, quad, lcol, flag, acc);

    // ---- epilogue: per-lane best/second over its 8 codes, then shuffle ----
    float s1[4][4], s2[4][4]; int k1[4][4];
    #pragma unroll
    for (int mt = 0; mt < 4; ++mt)
        #pragma unroll
        for (int r = 0; r < 4; ++r) { s1[mt][r] = 1e30f; s2[mt][r] = 1e30f; k1[mt][r] = 511; }
    #pragma unroll
    for (int j = 0; j < 8; ++j) {
        int code = (wave * 8 + j) * 16 + lcol;
        float wk = w2[code];
        #pragma unroll
        for (int mt = 0; mt < 4; ++mt)
            #pragma unroll
            for (int r = 0; r < 4; ++r) {
                float s = wk - 2.f * acc[mt][j][r];
                bmerge(s1[mt][r], k1[mt][r], s2[mt][r], s, code, 1e30f);
            }
    }
    // overlay reduction arrays on patch region (patch dead after last conv+bar)
    float* sS1 = (float*)smc;             // [64 pos][4 wave]
    int*   sK1 = (int*)(smc + 1024);
    float* sS2 = (float*)(smc + 2048);
    int*   ii  = (int*)(smc + 3072);      // [64]
    #pragma unroll
    for (int mt = 0; mt < 4; ++mt)
        #pragma unroll
        for (int r = 0; r < 4; ++r) {
            float a1 = s1[mt][r], a2 = s2[mt][r]; int ak = k1[mt][r];
            #pragma unroll
            for (int m = 1; m < 16; m <<= 1) {
                float o1 = __shfl_xor(a1, m);
                float o2 = __shfl_xor(a2, m);
                int   ok = __shfl_xor(ak, m);
                bmerge(a1, ak, a2, o1, ok, o2);
            }
            if (lcol == 0) {
                int pos = mt * 16 + quad * 4 + r;
                sS1[pos * 4 + wave] = a1;
                sK1[pos * 4 + wave] = ak;
                sS2[pos * 4 + wave] = a2;
            }
        }
    __syncthreads();
    if (t < 64) {
        float a1 = sS1[t * 4]; int ak = sK1[t * 4]; float a2 = sS2[t * 4];
        #pragma unroll
        for (int w = 1; w < 4; ++w)
            bmerge(a1, ak, a2, sS1[t * 4 + w], sK1[t * 4 + w], sS2[t * 4 + w]);
        ak &= 511;
        ii[t] = ak;
        unsigned int flagged = 0u;
        if (a2 - a1 < EPS_GAP) {
            int slot = atomicAdd(scnt, 1);
            if (slot < MAXSUS) { spos[slot] = P0 + t; flagged = 1u; }
        }
        idx[P0 + t] = (int)((unsigned)ak | (flagged << 31));
    }
    __syncthreads();

    // ---- fused emb: out_e[b][d][SP0+sp] = cbT[ii[sp]][d] ----
    const int sp = t & 63, dq = t >> 6;
    const float* row = cbT + (size_t)ii[sp] * 512;
    const size_t obase = ((size_t)b * 512) * 1024 + SP0 + sp;
    for (int d0 = dq * 128; d0 < dq * 128 + 128; d0 += 4) {
        if (skipTail && b == 31 && d0 >= 448) break;
        float4 v = *(const float4*)(row + d0);
        out_e[obase + (size_t)(d0    ) * 1024] = v.x;
        out_e[obase + (size_t)(d0 + 1) * 1024] = v.y;
        out_e[obase + (size_t)(d0 + 2) * 1024] = v.z;
        out_e[obase + (size_t)(d0 + 3) * 1024] = v.w;
    }
}

// ---------------------------------------------------------------------------
// FUSED post: recon (bid 0..127) ∥ rescore (bid 128..255) in one launch.
// ---------------------------------------------------------------------------
__global__ __launch_bounds__(256) void k_post(
        const float* __restrict__ out_z, const void* __restrict__ cb,
        const double* __restrict__ w2d, int* __restrict__ idx,
        const int* __restrict__ scnt, const int* __restrict__ spos,
        const float* __restrict__ U, const int* __restrict__ flagp,
        float* __restrict__ out_e, float* __restrict__ out_r, int skipTail) {
    __shared__ float zsh[512];
    __shared__ float rs[256];
    __shared__ int rk[256];
    __shared__ int bc[2];
    const int bid = blockIdx.x;
    const int t = threadIdx.x;

    if (bid < 128) {
        // ---- recon role ----
        const int pos = bid * 256 + t;
        const int v0 = idx[pos];
        if (v0 >= 0) {
            const int id = v0 & 511;
            const int b = pos >> 10, sp = pos & 1023, i = sp >> 5, j = sp & 31;
            const float* u = &U[(size_t)id * 48];
            #pragma unroll
            for (int c = 0; c < 3; ++c)
                #pragma unroll
                for (int uu = 0; uu < 4; ++uu) {
                    float4 q = *(const float4*)(&u[c * 16 + uu * 4]);
                    float4 o;
                    o.x = 1.f / (1.f + __expf(-q.x));
                    o.y = 1.f / (1.f + __expf(-q.y));
                    o.z = 1.f / (1.f + __expf(-q.z));
                    o.w = 1.f / (1.f + __expf(-q.w));
                    *(float4*)(&out_r[((size_t)((b * 3 + c) * 128) + (i * 4 + uu)) * 128 + j * 4]) = o;
                }
        }
        return;
    }

    // ---- rescore role ----
    const int flag = *flagp;
    int n = *scnt; if (n > MAXSUS) n = MAXSUS;
    for (int s = bid - 128; s < n; s += 128) {
        int p = spos[s] & 32767;
        int b = p >> 10, sp = p & 1023;
        __syncthreads();
        zsh[t]       = out_z[(size_t)(b * 512 + t) * 1024 + sp];
        zsh[t + 256] = out_z[(size_t)(b * 512 + t + 256) * 1024 + sp];
        __syncthreads();
        float bs = 1e30f; int bk = 511;
        for (int cc = 0; cc < 2; ++cc) {
            int k = t + cc * 256;
            double a = 0.0;
            for (int d = 0; d < 512; ++d)
                a = fma((double)zsh[d], (double)ldin(cb, (size_t)d * 512 + k, flag), a);
            float sc = (float)(w2d[k] - 2.0 * a);
            if (sc < bs || (sc == bs && k < bk)) { bs = sc; bk = k; }
        }
        rs[t] = bs; rk[t] = bk;
        __syncthreads();
        for (int str = 128; str > 0; str >>= 1) {
            if (t < str) {
                float so = rs[t + str]; int ko = rk[t + str];
                if (so < rs[t] || (so == rs[t] && ko < rk[t])) { rs[t] = so; rk[t] = ko; }
            }
            __syncthreads();
        }
        if (t == 0) {
            int kstar = rk[0] & 511;
            int old = idx[p] & 511;
            bc[0] = kstar; bc[1] = (kstar != old);
            idx[p] = kstar;                       // clears suspect flag too
        }
        __syncthreads();
        const int kk = bc[0];
        if (bc[1]) {
            for (int d = t; d < 512; d += 256) {
                if (skipTail && b == 31 && d >= 448) continue;
                out_e[(size_t)(b * 512 + d) * 1024 + sp] = ldin(cb, (size_t)d * 512 + kk, flag);
            }
        }
        // recon for this suspect (recon role skipped it) — always write
        if (t < 48) {
            float q = U[(size_t)kk * 48 + t];
            float o = 1.f / (1.f + __expf(-q));
            int c = t >> 4, uu = (t >> 2) & 3, vv = t & 3;
            int i = sp >> 5, j = sp & 31;
            out_r[((size_t)((b * 3 + c) * 128) + (i * 4 + uu)) * 128 + j * 4 + vv] = o;
        }
    }
}

// ---------------------------------------------------------------------------
__global__ __launch_bounds__(1024) void k_fixup(
        const void* __restrict__ cb, const int* __restrict__ flagp,
        const int* __restrict__ idx, float* __restrict__ out_e) {
    __shared__ int ii[1024];
    __shared__ int sflag;
    const int t = threadIdx.x;
    if (t == 0) sflag = *flagp;
    ii[t] = idx[31744 + t] & 511;
    __syncthreads();
    const int flag = sflag;
    for (int e = t; e < 65536; e += 1024) {
        int d = 448 + (e >> 10), sp = e & 1023;
        out_e[((size_t)(31 * 512 + d)) * 1024 + sp] = ldin(cb, (size_t)d * 512 + ii[sp], flag);
    }
}

// ---------------------------------------------------------------------------
extern "C" void kernel_launch(void* const* d_in, const int* in_sizes, int n_in,
                              void* d_out, int out_size, void* d_ws, size_t ws_size,
                              hipStream_t stream) {
    const void* x  = d_in[0];
    const void* We = d_in[1];
    const void* be = d_in[2];
    const void* Wd = d_in[3];
    const void* bd = d_in[4];
    const void* cb = d_in[5];

    float* out   = (float*)d_out;
    float* out_r = out;                       // 1,572,864 fp32 (6.29 MB)
    float* out_z = out + 1572864;             // 16,777,216 fp32
    float* out_e = out + 18350080;            // 16,777,216 fp32

    // Read-mostly tables in out_r (recon overwrites during k_post; nothing in
    // k_post reads them — rescore uses raw cb):
    char* Rb = (char*)out_r;
    float* cbT          = (float*)(Rb);                    // 1,048,576 B
    float* cWe          = (float*)(Rb + 1048576);          //    98,304 B
    float* cbe          = (float*)(Rb + 1146880);          //     2,048 B
    float* cWd          = (float*)(Rb + 1148928);          //    98,304 B
    float* cbd          = (float*)(Rb + 1247232);          //        64 B
    unsigned short* cbHS= (unsigned short*)(Rb + 1247296); //   524,288 B (swizzled)
    unsigned short* cbLS= (unsigned short*)(Rb + 1771584); //   524,288 B (swizzled)

    // Tail scratch: prefer d_ws; else last 256 KB of out_e (fixup required).
    int tailWS = (ws_size >= 262144) ? 1 : 0;
    char* Tbase = tailWS ? (char*)d_ws : ((char*)out_e + 66846720);
    int skipTail = tailWS ? 0 : 1;
    int*    idx  = (int*)   (Tbase);            // 131,072 B
    float*  U    = (float*) (Tbase + 131072);   //  98,304 B
    float*  w2   = (float*) (Tbase + 229376);   //   2,048 B
    double* w2d  = (double*)(Tbase + 231424);   //   4,096 B
    int*    flag = (int*)   (Tbase + 235520);   //      64 B
    int*    scnt = (int*)   (Tbase + 235584);   //      64 B
    int*    spos = (int*)   (Tbase + 235648);   //  16,384 B

    k_sniff<<<1, 1024, 0, stream>>>(cb, flag, scnt);
    k_prepAll<<<395, 256, 0, stream>>>(We, be, Wd, bd, cb, flag,
                                       cWe, cbe, cWd, cbd,
                                       cbT, cbHS, cbLS, w2, w2d, U);
    k_main<<<512, 256, 0, stream>>>(x, cWe, cbe, flag, cbHS, cbLS, cbT, w2,
                                    out_z, out_e, idx, scnt, spos, skipTail);
    k_post<<<256, 256, 0, stream>>>(out_z, cb, w2d, idx, scnt, spos, U, flag,
                                    out_e, out_r, skipTail);
    if (skipTail)
        k_fixup<<<1, 1024, 0, stream>>>(cb, flag, idx, out_e);
}